// Round 1
// 584.013 us; speedup vs baseline: 1.0583x; 1.0583x over previous
//
#include <hip/hip_runtime.h>
#include <hip/hip_bf16.h>

#define L   2304
#define D   256
#define NHD 8
#define HD  32
#define FF  1024
#define HH  48
#define WWW 48
#define SPL 4     // attention split-K factor

typedef unsigned short bfraw;
typedef __attribute__((ext_vector_type(8))) short s8v;   // 8 bf16 = 4 VGPRs
typedef __attribute__((ext_vector_type(4))) float f4v;   // MFMA C/D frag

__device__ __forceinline__ bfraw f2b(float x) {
    __hip_bfloat16 h = __float2bfloat16(x);
    return __builtin_bit_cast(bfraw, h);
}

// Diagnostic: fill output with a constant (decodable from reported absmax).
__global__ __launch_bounds__(256) void diag_kernel(float* __restrict__ out, float c, int n)
{
    int i = blockIdx.x * 256 + threadIdx.x;
    if (i < n) out[i] = c;
}

// ---------------------------------------------------------------------------
// LayerNorm over D=256, fp32 (+ optional bf16 secondary output).
// ---------------------------------------------------------------------------
__global__ __launch_bounds__(256) void ln_kernel(
    const float* __restrict__ inA, const float* __restrict__ inB,
    const float* __restrict__ g, const float* __restrict__ b,
    float* __restrict__ out, bfraw* __restrict__ outb)
{
    int row = blockIdx.x, t = threadIdx.x;
    size_t idx = (size_t)row * D + t;
    float v = inA[idx];
    if (inB) v += inB[idx];
    __shared__ float rs[256], rq[256];
    rs[t] = v; rq[t] = v * v;
    __syncthreads();
    for (int o = 128; o > 0; o >>= 1) {
        if (t < o) { rs[t] += rs[t + o]; rq[t] += rq[t + o]; }
        __syncthreads();
    }
    float mean = rs[0] * (1.f / D);
    float var  = rq[0] * (1.f / D) - mean * mean;
    float rstd = rsqrtf(var + 1e-5f);
    float r = (v - mean) * rstd * g[t] + b[t];
    out[idx] = r;
    if (outb) outb[idx] = f2b(r);
}

// ---------------------------------------------------------------------------
// Tiled fp32 GEMM: C[M,N] = A[M,K] @ W[N,K]^T + bias (+res). 64x64 tile.
// Optional bf16 secondary output outb (fuses the cvt pass).
// ---------------------------------------------------------------------------
__global__ __launch_bounds__(256) void gemm_tiled(
    const float* __restrict__ A, const float* __restrict__ W,
    const float* __restrict__ bias, const float* res, float* out,
    bfraw* __restrict__ outb,
    int M, int N, int K)
{
    __shared__ float As[16][68];
    __shared__ float Ws[16][68];
    int t = threadIdx.x;
    int tx = t & 15, ty = t >> 4;
    int m0 = blockIdx.x * 64, n0 = blockIdx.y * 64;
    int lr = t >> 2, lg = t & 3;
    float acc[4][4] = {{0.f}};
    const float* ap = A + (size_t)(m0 + lr) * K + lg * 4;
    const float* wp = W + (size_t)(n0 + lr) * K + lg * 4;
    for (int k0 = 0; k0 < K; k0 += 16) {
        float4 a4 = *reinterpret_cast<const float4*>(ap + k0);
        float4 w4 = *reinterpret_cast<const float4*>(wp + k0);
        __syncthreads();
        As[lg*4+0][lr] = a4.x; As[lg*4+1][lr] = a4.y;
        As[lg*4+2][lr] = a4.z; As[lg*4+3][lr] = a4.w;
        Ws[lg*4+0][lr] = w4.x; Ws[lg*4+1][lr] = w4.y;
        Ws[lg*4+2][lr] = w4.z; Ws[lg*4+3][lr] = w4.w;
        __syncthreads();
        #pragma unroll
        for (int kk = 0; kk < 16; kk++) {
            float4 av = *reinterpret_cast<const float4*>(&As[kk][ty * 4]);
            float4 bv = *reinterpret_cast<const float4*>(&Ws[kk][tx * 4]);
            acc[0][0] += av.x*bv.x; acc[0][1] += av.x*bv.y; acc[0][2] += av.x*bv.z; acc[0][3] += av.x*bv.w;
            acc[1][0] += av.y*bv.x; acc[1][1] += av.y*bv.y; acc[1][2] += av.y*bv.z; acc[1][3] += av.y*bv.w;
            acc[2][0] += av.z*bv.x; acc[2][1] += av.z*bv.y; acc[2][2] += av.z*bv.z; acc[2][3] += av.z*bv.w;
            acc[3][0] += av.w*bv.x; acc[3][1] += av.w*bv.y; acc[3][2] += av.w*bv.z; acc[3][3] += av.w*bv.w;
        }
    }
    #pragma unroll
    for (int i = 0; i < 4; i++) {
        int r = m0 + ty * 4 + i;
        #pragma unroll
        for (int j = 0; j < 4; j++) {
            int c = n0 + tx * 4 + j;
            float v = acc[i][j] + bias[c];
            size_t idx = (size_t)r * N + c;
            if (res) v += res[idx];
            out[idx] = v;
            if (outb) outb[idx] = f2b(v);
        }
    }
}

// fp32 [n] -> bf16 [n], vectorized (n % 1024 == 0).
__global__ __launch_bounds__(256) void cvt_kernel(
    const float* __restrict__ in, bfraw* __restrict__ out)
{
    size_t i = ((size_t)blockIdx.x * 256 + threadIdx.x) * 4;
    float4 v = *reinterpret_cast<const float4*>(in + i);
    ushort4 o;
    o.x = f2b(v.x); o.y = f2b(v.y); o.z = f2b(v.z); o.w = f2b(v.w);
    *reinterpret_cast<ushort4*>(out + i) = o;
}

// fp32 [N][D] -> bf16 [NH][HD][N] (transposed per head). Grid (N/32, NH).
__global__ __launch_bounds__(256) void cvtT_kernel(
    const float* __restrict__ in, bfraw* __restrict__ out, int N)
{
    __shared__ float Ls[32][33];
    int h = blockIdx.y, n0 = blockIdx.x * 32, t = threadIdx.x;
    int nl = t >> 3, dq = t & 7;
    float4 v = *reinterpret_cast<const float4*>(in + (size_t)(n0 + nl) * D + h * HD + dq * 4);
    Ls[nl][dq*4+0] = v.x; Ls[nl][dq*4+1] = v.y;
    Ls[nl][dq*4+2] = v.z; Ls[nl][dq*4+3] = v.w;
    __syncthreads();
    int dl = t >> 3, nq = t & 7;
    ushort4 o;
    o.x = f2b(Ls[nq*4+0][dl]); o.y = f2b(Ls[nq*4+1][dl]);
    o.z = f2b(Ls[nq*4+2][dl]); o.w = f2b(Ls[nq*4+3][dl]);
    *reinterpret_cast<ushort4*>(out + (size_t)(h * HD + dl) * N + n0 + nq * 4) = o;
}

// ---------------------------------------------------------------------------
// MFMA flash attention, split-K. One wave per (16-query tile, head, split).
// blockIdx.z selects the key chunk [z*chunk, (z+1)*chunk). Writes
// UNNORMALIZED partial O to OP + z*L*D and (m, l) to ML. chunk % 64 == 0.
// Exact same per-chunk math as the verified R13 kernel.
// ---------------------------------------------------------------------------
__global__ __launch_bounds__(64) void attn_mfma_split(
    const bfraw* __restrict__ Qb, const bfraw* __restrict__ Kb,
    const bfraw* __restrict__ Vt, float* __restrict__ OP,
    float* __restrict__ ML, int Lk, int chunk, float scale)
{
    __shared__ short Ks[64][40];     // 80B row stride: 16B-aligned, <=2-way banks
    __shared__ short Vts[32][72];
    __shared__ short Ps[16][72];
    int l = threadIdx.x;
    int h = blockIdx.y, q0 = blockIdx.x * 16, z = blockIdx.z;
    int lo = l & 15, quad = l >> 4;
    int kb = z * chunk, ke = kb + chunk;

    s8v qf = *reinterpret_cast<const s8v*>(Qb + (size_t)(q0 + lo) * D + h * HD + quad * 8);

    float m_r = -1e30f, l_r = 0.f;
    f4v o0 = {0.f, 0.f, 0.f, 0.f}, o1 = {0.f, 0.f, 0.f, 0.f};

    for (int k0 = kb; k0 < ke; k0 += 64) {
        __syncthreads();
        #pragma unroll
        for (int f = 0; f < 4; f++) {
            int idx = f * 64 + l, key = idx >> 2, part = idx & 3;
            s8v kv = *reinterpret_cast<const s8v*>(Kb + (size_t)(k0 + key) * D + h * HD + part * 8);
            *reinterpret_cast<s8v*>(&Ks[key][part * 8]) = kv;
        }
        #pragma unroll
        for (int f = 0; f < 4; f++) {
            int idx = f * 64 + l, d = idx >> 3, part = idx & 7;
            s8v vv = *reinterpret_cast<const s8v*>(Vt + (size_t)(h * HD + d) * Lk + k0 + part * 8);
            *reinterpret_cast<s8v*>(&Vts[d][part * 8]) = vv;
        }
        __syncthreads();

        f4v sc4[4];
        #pragma unroll
        for (int s = 0; s < 4; s++) {
            s8v kf = *reinterpret_cast<const s8v*>(&Ks[lo + 16 * s][quad * 8]);
            sc4[s] = __builtin_amdgcn_mfma_f32_16x16x32_bf16(kf, qf, (f4v){0.f,0.f,0.f,0.f}, 0, 0, 0);
        }
        float cm = -1e30f;
        #pragma unroll
        for (int s = 0; s < 4; s++)
            #pragma unroll
            for (int r = 0; r < 4; r++) {
                sc4[s][r] *= scale;
                cm = fmaxf(cm, sc4[s][r]);
            }
        cm = fmaxf(cm, __shfl_xor(cm, 16));
        cm = fmaxf(cm, __shfl_xor(cm, 32));
        float mnew = fmaxf(m_r, cm);
        float alpha = __expf(m_r - mnew);
        float ls = 0.f;
        #pragma unroll
        for (int s = 0; s < 4; s++) {
            float p0 = __expf(sc4[s][0] - mnew), p1 = __expf(sc4[s][1] - mnew);
            float p2 = __expf(sc4[s][2] - mnew), p3 = __expf(sc4[s][3] - mnew);
            ls += p0 + p1 + p2 + p3;
            ushort4 pk;
            pk.x = f2b(p0); pk.y = f2b(p1); pk.z = f2b(p2); pk.w = f2b(p3);
            *reinterpret_cast<ushort4*>(&Ps[lo][s * 16 + quad * 4]) = pk;
        }
        ls += __shfl_xor(ls, 16);
        ls += __shfl_xor(ls, 32);
        l_r = l_r * alpha + ls;
        m_r = mnew;
        #pragma unroll
        for (int r = 0; r < 4; r++) {
            float a = __shfl(alpha, quad * 4 + r);
            o0[r] *= a; o1[r] *= a;
        }
        __syncthreads();
        #pragma unroll
        for (int kc = 0; kc < 2; kc++) {
            s8v pf = *reinterpret_cast<const s8v*>(&Ps[lo][kc * 32 + quad * 8]);
            s8v v0 = *reinterpret_cast<const s8v*>(&Vts[lo][kc * 32 + quad * 8]);
            s8v v1 = *reinterpret_cast<const s8v*>(&Vts[16 + lo][kc * 32 + quad * 8]);
            o0 = __builtin_amdgcn_mfma_f32_16x16x32_bf16(pf, v0, o0, 0, 0, 0);
            o1 = __builtin_amdgcn_mfma_f32_16x16x32_bf16(pf, v1, o1, 0, 0, 0);
        }
    }

    float* Oz = OP + (size_t)z * L * D;
    #pragma unroll
    for (int r = 0; r < 4; r++) {
        int qg = q0 + quad * 4 + r;
        Oz[(size_t)qg * D + h * HD + lo]      = o0[r];   // unnormalized
        Oz[(size_t)qg * D + h * HD + 16 + lo] = o1[r];
    }
    if (l < 16) {
        size_t mi = (((size_t)z * NHD + h) * L + q0 + lo) * 2;
        ML[mi]     = m_r;
        ML[mi + 1] = l_r;
    }
}

// Merge SPL split-K partials: exact online-softmax combine.
// Grid (L), 256 threads; thread t handles head t>>5, dim t&31.
__global__ __launch_bounds__(256) void attn_combine(
    const float* __restrict__ OP, const float* __restrict__ ML,
    float* __restrict__ O)
{
    int q = blockIdx.x, t = threadIdx.x, h = t >> 5;
    float m[SPL], lv[SPL];
    float M = -1e30f;
    #pragma unroll
    for (int s = 0; s < SPL; s++) {
        size_t mi = (((size_t)s * NHD + h) * L + q) * 2;
        m[s]  = ML[mi];
        lv[s] = ML[mi + 1];
        M = fmaxf(M, m[s]);
    }
    float wl = 0.f, acc = 0.f;
    #pragma unroll
    for (int s = 0; s < SPL; s++) {
        float w = __expf(m[s] - M);
        wl  += w * lv[s];
        acc += w * OP[(size_t)s * L * D + (size_t)q * D + t];
    }
    O[(size_t)q * D + t] = acc / wl;
}

// ---------------------------------------------------------------------------
// GroupNorm stats over fp32 X [L, FF]: one block per group (32 ch x L).
// ---------------------------------------------------------------------------
__global__ __launch_bounds__(256) void gn_stats_kernel(
    const float* __restrict__ X, float* __restrict__ st)
{
    int g = blockIdx.x, t = threadIdx.x;
    int c = g * 32 + (t & 31);
    float s = 0.f, sq = 0.f;
    for (int l = (t >> 5); l < L; l += 8) {
        float v = X[(size_t)l * FF + c];
        s += v; sq += v * v;
    }
    __shared__ float rs[256], rq[256];
    rs[t] = s; rq[t] = sq;
    __syncthreads();
    for (int o = 128; o > 0; o >>= 1) {
        if (t < o) { rs[t] += rs[t + o]; rq[t] += rq[t + o]; }
        __syncthreads();
    }
    if (t == 0) {
        float n = (float)(L * 32);
        float mean = rs[0] / n;
        float var  = rq[0] / n - mean * mean;
        st[g * 2]     = mean;
        st[g * 2 + 1] = rsqrtf(var + 1e-5f);
    }
}

// ---------------------------------------------------------------------------
// Fused GN + exact-GELU + depthwise 5x5 conv. Grid (6,6,16):
// block = 8x8 spatial tile x 64 channels; stage 12x12 halo (GN+GELU applied,
// zero-padded AFTER activation) in LDS (36.9 KB); conv from LDS, write Y.
// Lane owns channel c = t&63 -> coalesced global, conflict-free LDS.
// ---------------------------------------------------------------------------
__global__ __launch_bounds__(256) void gn_gelu_dwconv(
    const float* __restrict__ X, const float* __restrict__ st,
    const float* __restrict__ gg, const float* __restrict__ gb,
    const float* __restrict__ Kw, float* __restrict__ Y)
{
    __shared__ float tile[144][64];
    int h0 = blockIdx.x * 8, w0 = blockIdx.y * 8, c0 = blockIdx.z * 64;
    int t = threadIdx.x;
    int c = t & 63;
    int cg = (c0 + c) >> 5;
    float mu = st[2 * cg], rs = st[2 * cg + 1];
    float ga = gg[c0 + c], be = gb[c0 + c];

    for (int i = t; i < 144 * 64; i += 256) {
        int sp = i >> 6;                       // 0..143 (i&63 == c)
        int hy = h0 + (sp / 12) - 2, wx = w0 + (sp % 12) - 2;
        float v = 0.f;
        if (hy >= 0 && hy < HH && wx >= 0 && wx < WWW) {
            float x = X[(size_t)(hy * WWW + wx) * FF + c0 + c];
            x = (x - mu) * rs * ga + be;
            v = 0.5f * x * (1.f + erff(x * 0.70710678118654752f));
        }
        tile[sp][c] = v;
    }
    float kw[25];
    #pragma unroll
    for (int i = 0; i < 25; i++) kw[i] = Kw[(size_t)(c0 + c) * 25 + i];
    __syncthreads();

    int sgrp = t >> 6;                         // 0..3, 16 outputs each
    for (int s = 0; s < 16; s++) {
        int sp = sgrp * 16 + s;                // 0..63
        int oh = sp >> 3, ow = sp & 7;
        float acc = 0.f;
        #pragma unroll
        for (int ky = 0; ky < 5; ky++)
            #pragma unroll
            for (int kx = 0; kx < 5; kx++)
                acc += tile[(oh + ky) * 12 + ow + kx][c] * kw[ky * 5 + kx];
        Y[(size_t)((h0 + oh) * WWW + w0 + ow) * FF + c0 + c] = acc;
    }
}

// ---------------------------------------------------------------------------
extern "C" void kernel_launch(void* const* d_in, const int* in_sizes, int n_in,
                              void* d_out, int out_size, void* d_ws, size_t ws_size,
                              hipStream_t stream)
{
    (void)in_sizes;
    float* out = (float*)d_out;   // reference output dtype is float32

    if (n_in != 34) {
        diag_kernel<<<(out_size + 255) / 256, 256, 0, stream>>>(out, 2000.f, out_size);
        return;
    }

    const float* tgt    = (const float*)d_in[0];
    const float* gK     = (const float*)d_in[1];
    const float* gV     = (const float*)d_in[2];
    const float* lK     = (const float*)d_in[3];
    const float* lV     = (const float*)d_in[4];
    const float* ln1_g  = (const float*)d_in[5];
    const float* ln1_b  = (const float*)d_in[6];
    const float* ln2_g  = (const float*)d_in[7];
    const float* ln2_b  = (const float*)d_in[8];
    const float* ln3_g  = (const float*)d_in[9];
    const float* ln3_b  = (const float*)d_in[10];
    const float* ln4_g  = (const float*)d_in[11];
    const float* ln4_b  = (const float*)d_in[12];
    const float* sa_Wq  = (const float*)d_in[13];
    const float* sa_bq  = (const float*)d_in[14];
    const float* sa_Wk  = (const float*)d_in[15];
    const float* sa_bk  = (const float*)d_in[16];
    const float* sa_Wv  = (const float*)d_in[17];
    const float* sa_bv  = (const float*)d_in[18];
    const float* sa_Wo  = (const float*)d_in[19];
    const float* sa_bo  = (const float*)d_in[20];
    const float* Wq     = (const float*)d_in[21];
    const float* bq     = (const float*)d_in[22];
    const float* lt_Wo  = (const float*)d_in[23];
    const float* lt_bo  = (const float*)d_in[24];
    const float* st_Wo  = (const float*)d_in[25];
    const float* st_bo  = (const float*)d_in[26];
    const float* W1w    = (const float*)d_in[27];
    const float* b1w    = (const float*)d_in[28];
    const float* gn_g   = (const float*)d_in[29];
    const float* gn_b   = (const float*)d_in[30];
    const float* dw_k   = (const float*)d_in[31];
    const float* W2w    = (const float*)d_in[32];
    const float* b2w    = (const float*)d_in[33];

    // Workspace (fp32): t0..t5 [L,D] + X2 [L,FF] + ST.
    // bf16 attention buffers alias X2 (dead until the stage-3 conv):
    //   qb[LD] | kb1[2LD] | vtb1[2LD] | kb2[LD] | vtb2[LD] = 7*LD bf16 (8.26MB)
    // Attention split-K partials: OP = t0..t3 (4*LD fp32, contiguous, dead
    // during each attention); ML lives in X2 slack after the bf16 buffers.
    const size_t LD = (size_t)L * D;
    const size_t NEED = (6 * LD + (size_t)L * FF + 64) * 4;
    float* ws = (float*)d_ws;
    float* t0 = ws + 0 * LD;
    float* t1 = ws + 1 * LD;
    float* t2 = ws + 2 * LD;
    float* t3 = ws + 3 * LD;
    float* t4 = ws + 4 * LD;
    float* t5 = ws + 5 * LD;
    float* X1 = t0;                   // [L,FF], spans t0..t3 (dead in stage 3)
    float* X2 = ws + 6 * LD;          // [L,FF]
    float* ST = X2 + (size_t)L * FF;  // 64 floats
    bfraw* qb   = (bfraw*)X2;
    bfraw* kb1  = qb + LD;            // gK bf16 (2L)
    bfraw* vtb1 = qb + 3 * LD;        // gV^T bf16 (2L)
    bfraw* kb2  = qb + 5 * LD;        // self/st K bf16 (L)
    bfraw* vtb2 = qb + 6 * LD;        // self/st V^T bf16 (L)
    float* OP   = ws;                 // split-K partials: [SPL][L][D] = t0..t3
    float* ML   = X2 + (7 * LD) / 2;  // [SPL][NHD][L][2] = 590KB (slack: 1.18MB)

    if (ws_size < NEED) {
        int wsMiB = (int)(ws_size >> 20); if (wsMiB > 63) wsMiB = 63;
        diag_kernel<<<(out_size + 255) / 256, 256, 0, stream>>>(out, 64.f + (float)wsMiB, out_size);
        return;
    }

    const float scale = 0.17677669529663687f;  // 1/sqrt(32)
    dim3 gDD(L / 64, D / 64);         // (36, 4)
    dim3 gDF(L / 64, FF / 64);        // (36, 16)
    dim3 gATS(L / 16, NHD, SPL);      // (144, 8, 4), 64-thread blocks
    int  cvtLD  = (int)(LD / 1024);
    dim3 gT1(L / 32, NHD);
    dim3 gT2(2 * L / 32, NHD);
    dim3 gDW(6, 6, 16);               // fused gn+gelu+dwconv

    // ---- stage 1: self attention ----
    ln_kernel<<<L, 256, 0, stream>>>(tgt, nullptr, ln1_g, ln1_b, t0, nullptr);
    gemm_tiled<<<gDD, 256, 0, stream>>>(t0, sa_Wq, sa_bq, nullptr, t1, qb,  L, D, D);
    gemm_tiled<<<gDD, 256, 0, stream>>>(t0, sa_Wk, sa_bk, nullptr, t2, kb2, L, D, D);
    gemm_tiled<<<gDD, 256, 0, stream>>>(t0, sa_Wv, sa_bv, nullptr, t3, nullptr, L, D, D);
    cvtT_kernel<<<gT1, 256, 0, stream>>>(t3, vtb2, L);
    // t0..t3 now dead -> split-K partials
    attn_mfma_split<<<gATS, 64, 0, stream>>>(qb, kb2, vtb2, OP, ML, L, L / SPL, scale);
    attn_combine<<<L, 256, 0, stream>>>(OP, ML, t4);
    gemm_tiled<<<gDD, 256, 0, stream>>>(t4, sa_Wo, sa_bo, tgt, t5, nullptr, L, D, D); // t5 = tgt + SA

    // ---- stage 2: long-term + short-term cross-attention ----
    ln_kernel<<<L, 256, 0, stream>>>(t5, nullptr, ln2_g, ln2_b, t0, nullptr);          // curr_V
    gemm_tiled<<<gDD, 256, 0, stream>>>(t0, Wq, bq, nullptr, t1, qb, L, D, D);         // curr_Q
    ln_kernel<<<L, 256, 0, stream>>>(t1, lK, ln4_g, ln4_b, t2, kb2);                   // k_st (+bf16)
    ln_kernel<<<L, 256, 0, stream>>>(t0, lV, ln4_g, ln4_b, t3, nullptr);               // v_st
    cvtT_kernel<<<gT1, 256, 0, stream>>>(t3, vtb2, L);                                 // frees t3
    cvt_kernel<<<2 * cvtLD, 256, 0, stream>>>(gK, kb1);
    cvtT_kernel<<<gT2, 256, 0, stream>>>(gV, vtb1, 2 * L);
    // t0..t3 now dead -> split-K partials
    attn_mfma_split<<<gATS, 64, 0, stream>>>(qb, kb1, vtb1, OP, ML, 2 * L, 2 * L / SPL, scale);
    attn_combine<<<L, 256, 0, stream>>>(OP, ML, t4);
    gemm_tiled<<<gDD, 256, 0, stream>>>(t4, lt_Wo, lt_bo, t5, t5, nullptr, L, D, D);   // t5 += lt
    attn_mfma_split<<<gATS, 64, 0, stream>>>(qb, kb2, vtb2, OP, ML, L, L / SPL, scale);
    attn_combine<<<L, 256, 0, stream>>>(OP, ML, t4);
    gemm_tiled<<<gDD, 256, 0, stream>>>(t4, st_Wo, st_bo, t5, t5, nullptr, L, D, D);   // t5 += st

    // ---- stage 3: FFN with fused GN + GELU + depthwise conv ----
    ln_kernel<<<L, 256, 0, stream>>>(t5, nullptr, ln3_g, ln3_b, t4, nullptr);          // ln3 (outside X1)
    gemm_tiled<<<gDF, 256, 0, stream>>>(t4, W1w, b1w, nullptr, X1, nullptr, L, FF, D);
    gn_stats_kernel<<<32, 256, 0, stream>>>(X1, ST);
    gn_gelu_dwconv<<<gDW, 256, 0, stream>>>(X1, ST, gn_g, gn_b, dw_k, X2);             // X2 = conv out
    gemm_tiled<<<gDD, 256, 0, stream>>>(X2, W2w, b2w, t5, out, nullptr, L, D, FF);     // out = t5 + FFN
}

// Round 2
// 507.410 us; speedup vs baseline: 1.2180x; 1.1510x over previous
//
#include <hip/hip_runtime.h>
#include <hip/hip_bf16.h>

#define L   2304
#define D   256
#define NHD 8
#define HD  32
#define FF  1024
#define HH  48
#define WWW 48
#define SPL 4     // attention split-K factor
#define RCH 24    // gn_stats row chunks
#define RP  (L / RCH)   // 96 rows per chunk

typedef unsigned short bfraw;
typedef __attribute__((ext_vector_type(8))) short s8v;   // 8 bf16 = 4 VGPRs
typedef __attribute__((ext_vector_type(4))) float f4v;   // MFMA C/D frag

__device__ __forceinline__ bfraw f2b(float x) {
    __hip_bfloat16 h = __float2bfloat16(x);
    return __builtin_bit_cast(bfraw, h);
}

// Diagnostic: fill output with a constant (decodable from reported absmax).
__global__ __launch_bounds__(256) void diag_kernel(float* __restrict__ out, float c, int n)
{
    int i = blockIdx.x * 256 + threadIdx.x;
    if (i < n) out[i] = c;
}

// ---------------------------------------------------------------------------
// LayerNorm over D=256, fp32 (+ optional bf16 secondary output).
// ---------------------------------------------------------------------------
__global__ __launch_bounds__(256) void ln_kernel(
    const float* __restrict__ inA, const float* __restrict__ inB,
    const float* __restrict__ g, const float* __restrict__ b,
    float* __restrict__ out, bfraw* __restrict__ outb)
{
    int row = blockIdx.x, t = threadIdx.x;
    size_t idx = (size_t)row * D + t;
    float v = inA[idx];
    if (inB) v += inB[idx];
    __shared__ float rs[256], rq[256];
    rs[t] = v; rq[t] = v * v;
    __syncthreads();
    for (int o = 128; o > 0; o >>= 1) {
        if (t < o) { rs[t] += rs[t + o]; rq[t] += rq[t + o]; }
        __syncthreads();
    }
    float mean = rs[0] * (1.f / D);
    float var  = rq[0] * (1.f / D) - mean * mean;
    float rstd = rsqrtf(var + 1e-5f);
    float r = (v - mean) * rstd * g[t] + b[t];
    out[idx] = r;
    if (outb) outb[idx] = f2b(r);
}

// ---------------------------------------------------------------------------
// Tiled fp32 GEMM: C[M,N] = A[M,K] @ W[N,K]^T + bias (+res). 64x64 tile.
// Optional bf16 secondary output outb (fuses the cvt pass).
// ---------------------------------------------------------------------------
__global__ __launch_bounds__(256) void gemm_tiled(
    const float* __restrict__ A, const float* __restrict__ W,
    const float* __restrict__ bias, const float* res, float* out,
    bfraw* __restrict__ outb,
    int M, int N, int K)
{
    __shared__ float As[16][68];
    __shared__ float Ws[16][68];
    int t = threadIdx.x;
    int tx = t & 15, ty = t >> 4;
    int m0 = blockIdx.x * 64, n0 = blockIdx.y * 64;
    int lr = t >> 2, lg = t & 3;
    float acc[4][4] = {{0.f}};
    const float* ap = A + (size_t)(m0 + lr) * K + lg * 4;
    const float* wp = W + (size_t)(n0 + lr) * K + lg * 4;
    for (int k0 = 0; k0 < K; k0 += 16) {
        float4 a4 = *reinterpret_cast<const float4*>(ap + k0);
        float4 w4 = *reinterpret_cast<const float4*>(wp + k0);
        __syncthreads();
        As[lg*4+0][lr] = a4.x; As[lg*4+1][lr] = a4.y;
        As[lg*4+2][lr] = a4.z; As[lg*4+3][lr] = a4.w;
        Ws[lg*4+0][lr] = w4.x; Ws[lg*4+1][lr] = w4.y;
        Ws[lg*4+2][lr] = w4.z; Ws[lg*4+3][lr] = w4.w;
        __syncthreads();
        #pragma unroll
        for (int kk = 0; kk < 16; kk++) {
            float4 av = *reinterpret_cast<const float4*>(&As[kk][ty * 4]);
            float4 bv = *reinterpret_cast<const float4*>(&Ws[kk][tx * 4]);
            acc[0][0] += av.x*bv.x; acc[0][1] += av.x*bv.y; acc[0][2] += av.x*bv.z; acc[0][3] += av.x*bv.w;
            acc[1][0] += av.y*bv.x; acc[1][1] += av.y*bv.y; acc[1][2] += av.y*bv.z; acc[1][3] += av.y*bv.w;
            acc[2][0] += av.z*bv.x; acc[2][1] += av.z*bv.y; acc[2][2] += av.z*bv.z; acc[2][3] += av.z*bv.w;
            acc[3][0] += av.w*bv.x; acc[3][1] += av.w*bv.y; acc[3][2] += av.w*bv.z; acc[3][3] += av.w*bv.w;
        }
    }
    #pragma unroll
    for (int i = 0; i < 4; i++) {
        int r = m0 + ty * 4 + i;
        #pragma unroll
        for (int j = 0; j < 4; j++) {
            int c = n0 + tx * 4 + j;
            float v = acc[i][j] + bias[c];
            size_t idx = (size_t)r * N + c;
            if (res) v += res[idx];
            out[idx] = v;
            if (outb) outb[idx] = f2b(v);
        }
    }
}

// fp32 [n] -> bf16 [n], vectorized (n % 1024 == 0).
__global__ __launch_bounds__(256) void cvt_kernel(
    const float* __restrict__ in, bfraw* __restrict__ out)
{
    size_t i = ((size_t)blockIdx.x * 256 + threadIdx.x) * 4;
    float4 v = *reinterpret_cast<const float4*>(in + i);
    ushort4 o;
    o.x = f2b(v.x); o.y = f2b(v.y); o.z = f2b(v.z); o.w = f2b(v.w);
    *reinterpret_cast<ushort4*>(out + i) = o;
}

// fp32 [N][D] -> bf16 [NH][HD][N] (transposed per head). Grid (N/32, NH).
__global__ __launch_bounds__(256) void cvtT_kernel(
    const float* __restrict__ in, bfraw* __restrict__ out, int N)
{
    __shared__ float Ls[32][33];
    int h = blockIdx.y, n0 = blockIdx.x * 32, t = threadIdx.x;
    int nl = t >> 3, dq = t & 7;
    float4 v = *reinterpret_cast<const float4*>(in + (size_t)(n0 + nl) * D + h * HD + dq * 4);
    Ls[nl][dq*4+0] = v.x; Ls[nl][dq*4+1] = v.y;
    Ls[nl][dq*4+2] = v.z; Ls[nl][dq*4+3] = v.w;
    __syncthreads();
    int dl = t >> 3, nq = t & 7;
    ushort4 o;
    o.x = f2b(Ls[nq*4+0][dl]); o.y = f2b(Ls[nq*4+1][dl]);
    o.z = f2b(Ls[nq*4+2][dl]); o.w = f2b(Ls[nq*4+3][dl]);
    *reinterpret_cast<ushort4*>(out + (size_t)(h * HD + dl) * N + n0 + nq * 4) = o;
}

// ---------------------------------------------------------------------------
// MFMA flash attention, split-K. One wave per (16-query tile, head, split).
// blockIdx.z selects the key chunk [z*chunk, (z+1)*chunk). Writes
// UNNORMALIZED partial O to OP + z*L*D and (m, l) to ML. chunk % 64 == 0.
// ---------------------------------------------------------------------------
__global__ __launch_bounds__(64) void attn_mfma_split(
    const bfraw* __restrict__ Qb, const bfraw* __restrict__ Kb,
    const bfraw* __restrict__ Vt, float* __restrict__ OP,
    float* __restrict__ ML, int Lk, int chunk, float scale)
{
    __shared__ short Ks[64][40];     // 80B row stride: 16B-aligned, <=2-way banks
    __shared__ short Vts[32][72];
    __shared__ short Ps[16][72];
    int l = threadIdx.x;
    int h = blockIdx.y, q0 = blockIdx.x * 16, z = blockIdx.z;
    int lo = l & 15, quad = l >> 4;
    int kb = z * chunk, ke = kb + chunk;

    s8v qf = *reinterpret_cast<const s8v*>(Qb + (size_t)(q0 + lo) * D + h * HD + quad * 8);

    float m_r = -1e30f, l_r = 0.f;
    f4v o0 = {0.f, 0.f, 0.f, 0.f}, o1 = {0.f, 0.f, 0.f, 0.f};

    for (int k0 = kb; k0 < ke; k0 += 64) {
        __syncthreads();
        #pragma unroll
        for (int f = 0; f < 4; f++) {
            int idx = f * 64 + l, key = idx >> 2, part = idx & 3;
            s8v kv = *reinterpret_cast<const s8v*>(Kb + (size_t)(k0 + key) * D + h * HD + part * 8);
            *reinterpret_cast<s8v*>(&Ks[key][part * 8]) = kv;
        }
        #pragma unroll
        for (int f = 0; f < 4; f++) {
            int idx = f * 64 + l, d = idx >> 3, part = idx & 7;
            s8v vv = *reinterpret_cast<const s8v*>(Vt + (size_t)(h * HD + d) * Lk + k0 + part * 8);
            *reinterpret_cast<s8v*>(&Vts[d][part * 8]) = vv;
        }
        __syncthreads();

        f4v sc4[4];
        #pragma unroll
        for (int s = 0; s < 4; s++) {
            s8v kf = *reinterpret_cast<const s8v*>(&Ks[lo + 16 * s][quad * 8]);
            sc4[s] = __builtin_amdgcn_mfma_f32_16x16x32_bf16(kf, qf, (f4v){0.f,0.f,0.f,0.f}, 0, 0, 0);
        }
        float cm = -1e30f;
        #pragma unroll
        for (int s = 0; s < 4; s++)
            #pragma unroll
            for (int r = 0; r < 4; r++) {
                sc4[s][r] *= scale;
                cm = fmaxf(cm, sc4[s][r]);
            }
        cm = fmaxf(cm, __shfl_xor(cm, 16));
        cm = fmaxf(cm, __shfl_xor(cm, 32));
        float mnew = fmaxf(m_r, cm);
        float alpha = __expf(m_r - mnew);
        float ls = 0.f;
        #pragma unroll
        for (int s = 0; s < 4; s++) {
            float p0 = __expf(sc4[s][0] - mnew), p1 = __expf(sc4[s][1] - mnew);
            float p2 = __expf(sc4[s][2] - mnew), p3 = __expf(sc4[s][3] - mnew);
            ls += p0 + p1 + p2 + p3;
            ushort4 pk;
            pk.x = f2b(p0); pk.y = f2b(p1); pk.z = f2b(p2); pk.w = f2b(p3);
            *reinterpret_cast<ushort4*>(&Ps[lo][s * 16 + quad * 4]) = pk;
        }
        ls += __shfl_xor(ls, 16);
        ls += __shfl_xor(ls, 32);
        l_r = l_r * alpha + ls;
        m_r = mnew;
        #pragma unroll
        for (int r = 0; r < 4; r++) {
            float a = __shfl(alpha, quad * 4 + r);
            o0[r] *= a; o1[r] *= a;
        }
        __syncthreads();
        #pragma unroll
        for (int kc = 0; kc < 2; kc++) {
            s8v pf = *reinterpret_cast<const s8v*>(&Ps[lo][kc * 32 + quad * 8]);
            s8v v0 = *reinterpret_cast<const s8v*>(&Vts[lo][kc * 32 + quad * 8]);
            s8v v1 = *reinterpret_cast<const s8v*>(&Vts[16 + lo][kc * 32 + quad * 8]);
            o0 = __builtin_amdgcn_mfma_f32_16x16x32_bf16(pf, v0, o0, 0, 0, 0);
            o1 = __builtin_amdgcn_mfma_f32_16x16x32_bf16(pf, v1, o1, 0, 0, 0);
        }
    }

    float* Oz = OP + (size_t)z * L * D;
    #pragma unroll
    for (int r = 0; r < 4; r++) {
        int qg = q0 + quad * 4 + r;
        Oz[(size_t)qg * D + h * HD + lo]      = o0[r];   // unnormalized
        Oz[(size_t)qg * D + h * HD + 16 + lo] = o1[r];
    }
    if (l < 16) {
        size_t mi = (((size_t)z * NHD + h) * L + q0 + lo) * 2;
        ML[mi]     = m_r;
        ML[mi + 1] = l_r;
    }
}

// Merge SPL split-K partials: exact online-softmax combine.
// Grid (L), 256 threads; thread t handles head t>>5, dim t&31.
__global__ __launch_bounds__(256) void attn_combine(
    const float* __restrict__ OP, const float* __restrict__ ML,
    float* __restrict__ O)
{
    int q = blockIdx.x, t = threadIdx.x, h = t >> 5;
    float m[SPL], lv[SPL];
    float M = -1e30f;
    #pragma unroll
    for (int s = 0; s < SPL; s++) {
        size_t mi = (((size_t)s * NHD + h) * L + q) * 2;
        m[s]  = ML[mi];
        lv[s] = ML[mi + 1];
        M = fmaxf(M, m[s]);
    }
    float wl = 0.f, acc = 0.f;
    #pragma unroll
    for (int s = 0; s < SPL; s++) {
        float w = __expf(m[s] - M);
        wl  += w * lv[s];
        acc += w * OP[(size_t)s * L * D + (size_t)q * D + t];
    }
    O[(size_t)q * D + t] = acc / wl;
}

// ---------------------------------------------------------------------------
// GroupNorm stats, two-stage. Stage A: grid (32, RCH); each block reduces a
// 96-row x 32-col slab of X [L, FF] to partial (sum, sumsq) in ps.
// ---------------------------------------------------------------------------
__global__ __launch_bounds__(256) void gn_stats_part(
    const float* __restrict__ X, float* __restrict__ ps)
{
    int g = blockIdx.x, rc = blockIdx.y, t = threadIdx.x;
    int cq = (t & 7) * 4;            // col quad within group (0..28)
    int rl = t >> 3;                 // 0..31 row lane
    int r0 = rc * RP;
    float s = 0.f, sq = 0.f;
    #pragma unroll
    for (int p = 0; p < RP / 32; p++) {
        int l = r0 + p * 32 + rl;
        float4 v = *reinterpret_cast<const float4*>(X + (size_t)l * FF + g * 32 + cq);
        s  += v.x + v.y + v.z + v.w;
        sq += v.x*v.x + v.y*v.y + v.z*v.z + v.w*v.w;
    }
    __shared__ float rs[256], rq[256];
    rs[t] = s; rq[t] = sq;
    __syncthreads();
    for (int o = 128; o > 0; o >>= 1) {
        if (t < o) { rs[t] += rs[t + o]; rq[t] += rq[t + o]; }
        __syncthreads();
    }
    if (t == 0) {
        ps[(g * RCH + rc) * 2]     = rs[0];
        ps[(g * RCH + rc) * 2 + 1] = rq[0];
    }
}

// Stage B: one block; thread g<32 folds RCH partials into mean/rstd.
__global__ __launch_bounds__(64) void gn_stats_final(
    const float* __restrict__ ps, float* __restrict__ st)
{
    int g = threadIdx.x;
    if (g < 32) {
        float s = 0.f, sq = 0.f;
        for (int i = 0; i < RCH; i++) {
            s  += ps[(g * RCH + i) * 2];
            sq += ps[(g * RCH + i) * 2 + 1];
        }
        float n = (float)(L * 32);
        float mean = s / n;
        float var  = sq / n - mean * mean;
        st[g * 2]     = mean;
        st[g * 2 + 1] = rsqrtf(var + 1e-5f);
    }
}

// ---------------------------------------------------------------------------
// Fused GN + exact-GELU + depthwise 5x5 conv. Grid (6,6,16):
// block = 8x8 spatial tile x 64 channels; stage 12x12 halo (GN+GELU applied,
// zero-padded AFTER activation) in LDS (36.9 KB); conv from LDS, write Y.
// Lane owns channel c = t&63 -> coalesced global, conflict-free LDS.
// ---------------------------------------------------------------------------
__global__ __launch_bounds__(256) void gn_gelu_dwconv(
    const float* __restrict__ X, const float* __restrict__ st,
    const float* __restrict__ gg, const float* __restrict__ gb,
    const float* __restrict__ Kw, float* __restrict__ Y)
{
    __shared__ float tile[144][64];
    int h0 = blockIdx.x * 8, w0 = blockIdx.y * 8, c0 = blockIdx.z * 64;
    int t = threadIdx.x;
    int c = t & 63;
    int cg = (c0 + c) >> 5;
    float mu = st[2 * cg], rs = st[2 * cg + 1];
    float ga = gg[c0 + c], be = gb[c0 + c];

    for (int i = t; i < 144 * 64; i += 256) {
        int sp = i >> 6;                       // 0..143 (i&63 == c)
        int hy = h0 + (sp / 12) - 2, wx = w0 + (sp % 12) - 2;
        float v = 0.f;
        if (hy >= 0 && hy < HH && wx >= 0 && wx < WWW) {
            float x = X[(size_t)(hy * WWW + wx) * FF + c0 + c];
            x = (x - mu) * rs * ga + be;
            v = 0.5f * x * (1.f + erff(x * 0.70710678118654752f));
        }
        tile[sp][c] = v;
    }
    float kw[25];
    #pragma unroll
    for (int i = 0; i < 25; i++) kw[i] = Kw[(size_t)(c0 + c) * 25 + i];
    __syncthreads();

    int sgrp = t >> 6;                         // 0..3, 16 outputs each
    for (int s = 0; s < 16; s++) {
        int sp = sgrp * 16 + s;                // 0..63
        int oh = sp >> 3, ow = sp & 7;
        float acc = 0.f;
        #pragma unroll
        for (int ky = 0; ky < 5; ky++)
            #pragma unroll
            for (int kx = 0; kx < 5; kx++)
                acc += tile[(oh + ky) * 12 + ow + kx][c] * kw[ky * 5 + kx];
        Y[(size_t)((h0 + oh) * WWW + w0 + ow) * FF + c0 + c] = acc;
    }
}

// ---------------------------------------------------------------------------
extern "C" void kernel_launch(void* const* d_in, const int* in_sizes, int n_in,
                              void* d_out, int out_size, void* d_ws, size_t ws_size,
                              hipStream_t stream)
{
    (void)in_sizes;
    float* out = (float*)d_out;   // reference output dtype is float32

    if (n_in != 34) {
        diag_kernel<<<(out_size + 255) / 256, 256, 0, stream>>>(out, 2000.f, out_size);
        return;
    }

    const float* tgt    = (const float*)d_in[0];
    const float* gK     = (const float*)d_in[1];
    const float* gV     = (const float*)d_in[2];
    const float* lK     = (const float*)d_in[3];
    const float* lV     = (const float*)d_in[4];
    const float* ln1_g  = (const float*)d_in[5];
    const float* ln1_b  = (const float*)d_in[6];
    const float* ln2_g  = (const float*)d_in[7];
    const float* ln2_b  = (const float*)d_in[8];
    const float* ln3_g  = (const float*)d_in[9];
    const float* ln3_b  = (const float*)d_in[10];
    const float* ln4_g  = (const float*)d_in[11];
    const float* ln4_b  = (const float*)d_in[12];
    const float* sa_Wq  = (const float*)d_in[13];
    const float* sa_bq  = (const float*)d_in[14];
    const float* sa_Wk  = (const float*)d_in[15];
    const float* sa_bk  = (const float*)d_in[16];
    const float* sa_Wv  = (const float*)d_in[17];
    const float* sa_bv  = (const float*)d_in[18];
    const float* sa_Wo  = (const float*)d_in[19];
    const float* sa_bo  = (const float*)d_in[20];
    const float* Wq     = (const float*)d_in[21];
    const float* bq     = (const float*)d_in[22];
    const float* lt_Wo  = (const float*)d_in[23];
    const float* lt_bo  = (const float*)d_in[24];
    const float* st_Wo  = (const float*)d_in[25];
    const float* st_bo  = (const float*)d_in[26];
    const float* W1w    = (const float*)d_in[27];
    const float* b1w    = (const float*)d_in[28];
    const float* gn_g   = (const float*)d_in[29];
    const float* gn_b   = (const float*)d_in[30];
    const float* dw_k   = (const float*)d_in[31];
    const float* W2w    = (const float*)d_in[32];
    const float* b2w    = (const float*)d_in[33];

    // Workspace (fp32): t0..t5 [L,D] + X2 [L,FF] + ST.
    // bf16 attention buffers alias X2 (dead until the stage-3 conv):
    //   qb[LD] | kb1[2LD] | vtb1[2LD] | kb2[LD] | vtb2[LD] = 7*LD bf16 (8.26MB)
    // Attention split-K partials: OP = t0..t3 (4*LD fp32, contiguous, dead
    // during each attention); ML lives in X2 slack after the bf16 buffers.
    // gn_stats partials PS reuse the (dead in stage 3) ML slot.
    const size_t LD = (size_t)L * D;
    const size_t NEED = (6 * LD + (size_t)L * FF + 64) * 4;
    float* ws = (float*)d_ws;
    float* t0 = ws + 0 * LD;
    float* t1 = ws + 1 * LD;
    float* t2 = ws + 2 * LD;
    float* t3 = ws + 3 * LD;
    float* t4 = ws + 4 * LD;
    float* t5 = ws + 5 * LD;
    float* X1 = t0;                   // [L,FF], spans t0..t3 (dead in stage 3)
    float* X2 = ws + 6 * LD;          // [L,FF]
    float* ST = X2 + (size_t)L * FF;  // 64 floats
    bfraw* qb   = (bfraw*)X2;
    bfraw* kb1  = qb + LD;            // gK bf16 (2L)
    bfraw* vtb1 = qb + 3 * LD;        // gV^T bf16 (2L)
    bfraw* kb2  = qb + 5 * LD;        // self/st K bf16 (L)
    bfraw* vtb2 = qb + 6 * LD;        // self/st V^T bf16 (L)
    float* OP   = ws;                 // split-K partials: [SPL][L][D] = t0..t3
    float* ML   = X2 + (7 * LD) / 2;  // [SPL][NHD][L][2] = 590KB (slack: 1.18MB)
    float* PS   = ML;                 // gn_stats partials [32][RCH][2] (stage 3)

    if (ws_size < NEED) {
        int wsMiB = (int)(ws_size >> 20); if (wsMiB > 63) wsMiB = 63;
        diag_kernel<<<(out_size + 255) / 256, 256, 0, stream>>>(out, 64.f + (float)wsMiB, out_size);
        return;
    }

    const float scale = 0.17677669529663687f;  // 1/sqrt(32)
    dim3 gDD(L / 64, D / 64);         // (36, 4)
    dim3 gDF(L / 64, FF / 64);        // (36, 16)
    dim3 gATS(L / 16, NHD, SPL);      // (144, 8, 4), 64-thread blocks
    int  cvtLD  = (int)(LD / 1024);
    dim3 gT1(L / 32, NHD);
    dim3 gT2(2 * L / 32, NHD);
    dim3 gGN(32, RCH);                // gn_stats stage A
    dim3 gDW(6, 6, 16);               // fused gn+gelu+dwconv

    // ---- stage 1: self attention ----
    ln_kernel<<<L, 256, 0, stream>>>(tgt, nullptr, ln1_g, ln1_b, t0, nullptr);
    gemm_tiled<<<gDD, 256, 0, stream>>>(t0, sa_Wq, sa_bq, nullptr, t1, qb,  L, D, D);
    gemm_tiled<<<gDD, 256, 0, stream>>>(t0, sa_Wk, sa_bk, nullptr, t2, kb2, L, D, D);
    gemm_tiled<<<gDD, 256, 0, stream>>>(t0, sa_Wv, sa_bv, nullptr, t3, nullptr, L, D, D);
    cvtT_kernel<<<gT1, 256, 0, stream>>>(t3, vtb2, L);
    // t0..t3 now dead -> split-K partials
    attn_mfma_split<<<gATS, 64, 0, stream>>>(qb, kb2, vtb2, OP, ML, L, L / SPL, scale);
    attn_combine<<<L, 256, 0, stream>>>(OP, ML, t4);
    gemm_tiled<<<gDD, 256, 0, stream>>>(t4, sa_Wo, sa_bo, tgt, t5, nullptr, L, D, D); // t5 = tgt + SA

    // ---- stage 2: long-term + short-term cross-attention ----
    ln_kernel<<<L, 256, 0, stream>>>(t5, nullptr, ln2_g, ln2_b, t0, nullptr);          // curr_V
    gemm_tiled<<<gDD, 256, 0, stream>>>(t0, Wq, bq, nullptr, t1, qb, L, D, D);         // curr_Q
    ln_kernel<<<L, 256, 0, stream>>>(t1, lK, ln4_g, ln4_b, t2, kb2);                   // k_st (+bf16)
    ln_kernel<<<L, 256, 0, stream>>>(t0, lV, ln4_g, ln4_b, t3, nullptr);               // v_st
    cvtT_kernel<<<gT1, 256, 0, stream>>>(t3, vtb2, L);                                 // frees t3
    cvt_kernel<<<2 * cvtLD, 256, 0, stream>>>(gK, kb1);
    cvtT_kernel<<<gT2, 256, 0, stream>>>(gV, vtb1, 2 * L);
    // t0..t3 now dead -> split-K partials
    attn_mfma_split<<<gATS, 64, 0, stream>>>(qb, kb1, vtb1, OP, ML, 2 * L, 2 * L / SPL, scale);
    attn_combine<<<L, 256, 0, stream>>>(OP, ML, t4);
    gemm_tiled<<<gDD, 256, 0, stream>>>(t4, lt_Wo, lt_bo, t5, t5, nullptr, L, D, D);   // t5 += lt
    attn_mfma_split<<<gATS, 64, 0, stream>>>(qb, kb2, vtb2, OP, ML, L, L / SPL, scale);
    attn_combine<<<L, 256, 0, stream>>>(OP, ML, t4);
    gemm_tiled<<<gDD, 256, 0, stream>>>(t4, st_Wo, st_bo, t5, t5, nullptr, L, D, D);   // t5 += st

    // ---- stage 3: FFN with fused GN + GELU + depthwise conv ----
    ln_kernel<<<L, 256, 0, stream>>>(t5, nullptr, ln3_g, ln3_b, t4, nullptr);          // ln3 (outside X1)
    gemm_tiled<<<gDF, 256, 0, stream>>>(t4, W1w, b1w, nullptr, X1, nullptr, L, FF, D);
    gn_stats_part<<<gGN, 256, 0, stream>>>(X1, PS);
    gn_stats_final<<<1, 64, 0, stream>>>(PS, ST);
    gn_gelu_dwconv<<<gDW, 256, 0, stream>>>(X1, ST, gn_g, gn_b, dw_k, X2);             // X2 = conv out
    gemm_tiled<<<gDD, 256, 0, stream>>>(X2, W2w, b2w, t5, out, nullptr, L, D, FF);     // out = t5 + FFN
}

// Round 3
// 401.158 us; speedup vs baseline: 1.5407x; 1.2649x over previous
//
#include <hip/hip_runtime.h>
#include <hip/hip_bf16.h>

#define L   2304
#define D   256
#define NHD 8
#define HD  32
#define FF  1024
#define HH  48
#define WWW 48
#define SPL 4     // attention split-K factor
#define RCH 24    // gn_stats row chunks
#define RP  (L / RCH)   // 96 rows per chunk

typedef unsigned short bfraw;
typedef __attribute__((ext_vector_type(8))) short s8v;   // 8 bf16 = 4 VGPRs
typedef __attribute__((ext_vector_type(4))) float f4v;   // MFMA C/D frag

__device__ __forceinline__ bfraw f2b(float x) {
    __hip_bfloat16 h = __float2bfloat16(x);
    return __builtin_bit_cast(bfraw, h);
}

// Diagnostic: fill output with a constant (decodable from reported absmax).
__global__ __launch_bounds__(256) void diag_kernel(float* __restrict__ out, float c, int n)
{
    int i = blockIdx.x * 256 + threadIdx.x;
    if (i < n) out[i] = c;
}

// ---------------------------------------------------------------------------
// LayerNorm over D=256, fp32 (+ optional bf16 secondary output).
// ---------------------------------------------------------------------------
__global__ __launch_bounds__(256) void ln_kernel(
    const float* __restrict__ inA, const float* __restrict__ inB,
    const float* __restrict__ g, const float* __restrict__ b,
    float* __restrict__ out, bfraw* __restrict__ outb)
{
    int row = blockIdx.x, t = threadIdx.x;
    size_t idx = (size_t)row * D + t;
    float v = inA[idx];
    if (inB) v += inB[idx];
    __shared__ float rs[256], rq[256];
    rs[t] = v; rq[t] = v * v;
    __syncthreads();
    for (int o = 128; o > 0; o >>= 1) {
        if (t < o) { rs[t] += rs[t + o]; rq[t] += rq[t + o]; }
        __syncthreads();
    }
    float mean = rs[0] * (1.f / D);
    float var  = rq[0] * (1.f / D) - mean * mean;
    float rstd = rsqrtf(var + 1e-5f);
    float r = (v - mean) * rstd * g[t] + b[t];
    out[idx] = r;
    if (outb) outb[idx] = f2b(r);
}

// ---------------------------------------------------------------------------
// MFMA bf16 GEMM: C[M,N] = A[M,K] @ W[N,K]^T + bias (+res), fp32 in/out.
// A and W are fp32 in global; converted to bf16 in-register during LDS
// staging. 64x64 tile, 4 waves (wave w -> rows w*16..+15, all 64 cols),
// BK=32, mfma_f32_16x16x32_bf16, fp32 accumulate.
// LDS XOR swizzle: 16B col group g stored at g ^ ((row>>2)&3)  -> <=2-way.
// Fragment orientation matches the verified attention kernel:
//   mfma(X,Y): D[row][col] = dot(X[row], Y[col]); row=(lane>>4)*4+reg,
//   col=lane&15. X=A-frag (m), Y=W-frag (n).
// ---------------------------------------------------------------------------
__global__ __launch_bounds__(256) void gemm_mfma(
    const float* __restrict__ A, const float* __restrict__ W,
    const float* __restrict__ bias, const float* res, float* out,
    bfraw* __restrict__ outb,
    int M, int N, int K)
{
    __shared__ __attribute__((aligned(16))) short Al[64][32];
    __shared__ __attribute__((aligned(16))) short Wl[64][32];
    int t = threadIdx.x;
    int w = t >> 6, l = t & 63;
    int lo = l & 15, quad = l >> 4;
    int m0 = blockIdx.x * 64, n0 = blockIdx.y * 64;
    f4v acc[4];
    #pragma unroll
    for (int j = 0; j < 4; j++) acc[j] = (f4v){0.f, 0.f, 0.f, 0.f};

    int aswz = (quad ^ ((lo >> 2) & 3)) * 8;   // swizzled k-group for frag reads

    for (int k0 = 0; k0 < K; k0 += 32) {
        float4 a4[2], w4[2];
        #pragma unroll
        for (int i = 0; i < 2; i++) {
            int idx = i * 256 + t, row = idx >> 3, part = idx & 7;
            a4[i] = *reinterpret_cast<const float4*>(A + (size_t)(m0 + row) * K + k0 + part * 4);
            w4[i] = *reinterpret_cast<const float4*>(W + (size_t)(n0 + row) * K + k0 + part * 4);
        }
        __syncthreads();
        #pragma unroll
        for (int i = 0; i < 2; i++) {
            int idx = i * 256 + t, row = idx >> 3, part = idx & 7;
            int col = ((part >> 1) ^ ((row >> 2) & 3)) * 8 + (part & 1) * 4;
            ushort4 ab, wb;
            ab.x = f2b(a4[i].x); ab.y = f2b(a4[i].y); ab.z = f2b(a4[i].z); ab.w = f2b(a4[i].w);
            wb.x = f2b(w4[i].x); wb.y = f2b(w4[i].y); wb.z = f2b(w4[i].z); wb.w = f2b(w4[i].w);
            *reinterpret_cast<ushort4*>(&Al[row][col]) = ab;
            *reinterpret_cast<ushort4*>(&Wl[row][col]) = wb;
        }
        __syncthreads();
        s8v af = *reinterpret_cast<const s8v*>(&Al[w * 16 + lo][aswz]);
        #pragma unroll
        for (int j = 0; j < 4; j++) {
            s8v wf = *reinterpret_cast<const s8v*>(&Wl[j * 16 + lo][aswz]);
            acc[j] = __builtin_amdgcn_mfma_f32_16x16x32_bf16(af, wf, acc[j], 0, 0, 0);
        }
    }

    #pragma unroll
    for (int j = 0; j < 4; j++) {
        #pragma unroll
        for (int r = 0; r < 4; r++) {
            int mrow = m0 + w * 16 + quad * 4 + r;
            int ncol = n0 + j * 16 + lo;
            float v = acc[j][r] + bias[ncol];
            size_t idx = (size_t)mrow * N + ncol;
            if (res) v += res[idx];
            out[idx] = v;
            if (outb) outb[idx] = f2b(v);
        }
    }
}

// fp32 [n] -> bf16 [n], vectorized (n % 1024 == 0).
__global__ __launch_bounds__(256) void cvt_kernel(
    const float* __restrict__ in, bfraw* __restrict__ out)
{
    size_t i = ((size_t)blockIdx.x * 256 + threadIdx.x) * 4;
    float4 v = *reinterpret_cast<const float4*>(in + i);
    ushort4 o;
    o.x = f2b(v.x); o.y = f2b(v.y); o.z = f2b(v.z); o.w = f2b(v.w);
    *reinterpret_cast<ushort4*>(out + i) = o;
}

// fp32 [N][D] -> bf16 [NH][HD][N] (transposed per head). Grid (N/32, NH).
__global__ __launch_bounds__(256) void cvtT_kernel(
    const float* __restrict__ in, bfraw* __restrict__ out, int N)
{
    __shared__ float Ls[32][33];
    int h = blockIdx.y, n0 = blockIdx.x * 32, t = threadIdx.x;
    int nl = t >> 3, dq = t & 7;
    float4 v = *reinterpret_cast<const float4*>(in + (size_t)(n0 + nl) * D + h * HD + dq * 4);
    Ls[nl][dq*4+0] = v.x; Ls[nl][dq*4+1] = v.y;
    Ls[nl][dq*4+2] = v.z; Ls[nl][dq*4+3] = v.w;
    __syncthreads();
    int dl = t >> 3, nq = t & 7;
    ushort4 o;
    o.x = f2b(Ls[nq*4+0][dl]); o.y = f2b(Ls[nq*4+1][dl]);
    o.z = f2b(Ls[nq*4+2][dl]); o.w = f2b(Ls[nq*4+3][dl]);
    *reinterpret_cast<ushort4*>(out + (size_t)(h * HD + dl) * N + n0 + nq * 4) = o;
}

// ---------------------------------------------------------------------------
// MFMA flash attention, split-K. One wave per (16-query tile, head, split).
// blockIdx.z selects the key chunk [z*chunk, (z+1)*chunk). Writes
// UNNORMALIZED partial O to OP + z*L*D and (m, l) to ML. chunk % 64 == 0.
// Ks uses 64B row stride + XOR swizzle (16B group g ^= (row>>2)&3):
// both write and read land at <=2-way bank aliasing (free, m136).
// ---------------------------------------------------------------------------
__global__ __launch_bounds__(64) void attn_mfma_split(
    const bfraw* __restrict__ Qb, const bfraw* __restrict__ Kb,
    const bfraw* __restrict__ Vt, float* __restrict__ OP,
    float* __restrict__ ML, int Lk, int chunk, float scale)
{
    __shared__ __attribute__((aligned(16))) short Ks[64][32];
    __shared__ __attribute__((aligned(16))) short Vts[32][72];
    __shared__ __attribute__((aligned(16))) short Ps[16][72];
    int l = threadIdx.x;
    int h = blockIdx.y, q0 = blockIdx.x * 16, z = blockIdx.z;
    int lo = l & 15, quad = l >> 4;
    int kb = z * chunk, ke = kb + chunk;

    s8v qf = *reinterpret_cast<const s8v*>(Qb + (size_t)(q0 + lo) * D + h * HD + quad * 8);
    int kswz = (quad ^ ((lo >> 2) & 3)) * 8;   // swizzled k-frag group

    float m_r = -1e30f, l_r = 0.f;
    f4v o0 = {0.f, 0.f, 0.f, 0.f}, o1 = {0.f, 0.f, 0.f, 0.f};

    for (int k0 = kb; k0 < ke; k0 += 64) {
        __syncthreads();
        #pragma unroll
        for (int f = 0; f < 4; f++) {
            int idx = f * 64 + l, key = idx >> 2, part = idx & 3;
            s8v kv = *reinterpret_cast<const s8v*>(Kb + (size_t)(k0 + key) * D + h * HD + part * 8);
            *reinterpret_cast<s8v*>(&Ks[key][(part ^ ((key >> 2) & 3)) * 8]) = kv;
        }
        #pragma unroll
        for (int f = 0; f < 4; f++) {
            int idx = f * 64 + l, d = idx >> 3, part = idx & 7;
            s8v vv = *reinterpret_cast<const s8v*>(Vt + (size_t)(h * HD + d) * Lk + k0 + part * 8);
            *reinterpret_cast<s8v*>(&Vts[d][part * 8]) = vv;
        }
        __syncthreads();

        f4v sc4[4];
        #pragma unroll
        for (int s = 0; s < 4; s++) {
            s8v kf = *reinterpret_cast<const s8v*>(&Ks[lo + 16 * s][kswz]);
            sc4[s] = __builtin_amdgcn_mfma_f32_16x16x32_bf16(kf, qf, (f4v){0.f,0.f,0.f,0.f}, 0, 0, 0);
        }
        float cm = -1e30f;
        #pragma unroll
        for (int s = 0; s < 4; s++)
            #pragma unroll
            for (int r = 0; r < 4; r++) {
                sc4[s][r] *= scale;
                cm = fmaxf(cm, sc4[s][r]);
            }
        cm = fmaxf(cm, __shfl_xor(cm, 16));
        cm = fmaxf(cm, __shfl_xor(cm, 32));
        float mnew = fmaxf(m_r, cm);
        float alpha = __expf(m_r - mnew);
        float ls = 0.f;
        #pragma unroll
        for (int s = 0; s < 4; s++) {
            float p0 = __expf(sc4[s][0] - mnew), p1 = __expf(sc4[s][1] - mnew);
            float p2 = __expf(sc4[s][2] - mnew), p3 = __expf(sc4[s][3] - mnew);
            ls += p0 + p1 + p2 + p3;
            ushort4 pk;
            pk.x = f2b(p0); pk.y = f2b(p1); pk.z = f2b(p2); pk.w = f2b(p3);
            *reinterpret_cast<ushort4*>(&Ps[lo][s * 16 + quad * 4]) = pk;
        }
        ls += __shfl_xor(ls, 16);
        ls += __shfl_xor(ls, 32);
        l_r = l_r * alpha + ls;
        m_r = mnew;
        #pragma unroll
        for (int r = 0; r < 4; r++) {
            float a = __shfl(alpha, quad * 4 + r);
            o0[r] *= a; o1[r] *= a;
        }
        __syncthreads();
        #pragma unroll
        for (int kc = 0; kc < 2; kc++) {
            s8v pf = *reinterpret_cast<const s8v*>(&Ps[lo][kc * 32 + quad * 8]);
            s8v v0 = *reinterpret_cast<const s8v*>(&Vts[lo][kc * 32 + quad * 8]);
            s8v v1 = *reinterpret_cast<const s8v*>(&Vts[16 + lo][kc * 32 + quad * 8]);
            o0 = __builtin_amdgcn_mfma_f32_16x16x32_bf16(pf, v0, o0, 0, 0, 0);
            o1 = __builtin_amdgcn_mfma_f32_16x16x32_bf16(pf, v1, o1, 0, 0, 0);
        }
    }

    float* Oz = OP + (size_t)z * L * D;
    #pragma unroll
    for (int r = 0; r < 4; r++) {
        int qg = q0 + quad * 4 + r;
        Oz[(size_t)qg * D + h * HD + lo]      = o0[r];   // unnormalized
        Oz[(size_t)qg * D + h * HD + 16 + lo] = o1[r];
    }
    if (l < 16) {
        size_t mi = (((size_t)z * NHD + h) * L + q0 + lo) * 2;
        ML[mi]     = m_r;
        ML[mi + 1] = l_r;
    }
}

// Merge SPL split-K partials: exact online-softmax combine.
// Grid (L), 256 threads; thread t handles head t>>5, dim t&31.
__global__ __launch_bounds__(256) void attn_combine(
    const float* __restrict__ OP, const float* __restrict__ ML,
    float* __restrict__ O)
{
    int q = blockIdx.x, t = threadIdx.x, h = t >> 5;
    float m[SPL], lv[SPL];
    float M = -1e30f;
    #pragma unroll
    for (int s = 0; s < SPL; s++) {
        size_t mi = (((size_t)s * NHD + h) * L + q) * 2;
        m[s]  = ML[mi];
        lv[s] = ML[mi + 1];
        M = fmaxf(M, m[s]);
    }
    float wl = 0.f, acc = 0.f;
    #pragma unroll
    for (int s = 0; s < SPL; s++) {
        float w = __expf(m[s] - M);
        wl  += w * lv[s];
        acc += w * OP[(size_t)s * L * D + (size_t)q * D + t];
    }
    O[(size_t)q * D + t] = acc / wl;
}

// ---------------------------------------------------------------------------
// GroupNorm stats, two-stage. Stage A: grid (32, RCH); each block reduces a
// 96-row x 32-col slab of X [L, FF] to partial (sum, sumsq) in ps.
// ---------------------------------------------------------------------------
__global__ __launch_bounds__(256) void gn_stats_part(
    const float* __restrict__ X, float* __restrict__ ps)
{
    int g = blockIdx.x, rc = blockIdx.y, t = threadIdx.x;
    int cq = (t & 7) * 4;            // col quad within group (0..28)
    int rl = t >> 3;                 // 0..31 row lane
    int r0 = rc * RP;
    float s = 0.f, sq = 0.f;
    #pragma unroll
    for (int p = 0; p < RP / 32; p++) {
        int l = r0 + p * 32 + rl;
        float4 v = *reinterpret_cast<const float4*>(X + (size_t)l * FF + g * 32 + cq);
        s  += v.x + v.y + v.z + v.w;
        sq += v.x*v.x + v.y*v.y + v.z*v.z + v.w*v.w;
    }
    __shared__ float rs[256], rq[256];
    rs[t] = s; rq[t] = sq;
    __syncthreads();
    for (int o = 128; o > 0; o >>= 1) {
        if (t < o) { rs[t] += rs[t + o]; rq[t] += rq[t + o]; }
        __syncthreads();
    }
    if (t == 0) {
        ps[(g * RCH + rc) * 2]     = rs[0];
        ps[(g * RCH + rc) * 2 + 1] = rq[0];
    }
}

// Stage B: one block; thread g<32 folds RCH partials into mean/rstd.
__global__ __launch_bounds__(64) void gn_stats_final(
    const float* __restrict__ ps, float* __restrict__ st)
{
    int g = threadIdx.x;
    if (g < 32) {
        float s = 0.f, sq = 0.f;
        for (int i = 0; i < RCH; i++) {
            s  += ps[(g * RCH + i) * 2];
            sq += ps[(g * RCH + i) * 2 + 1];
        }
        float n = (float)(L * 32);
        float mean = s / n;
        float var  = sq / n - mean * mean;
        st[g * 2]     = mean;
        st[g * 2 + 1] = rsqrtf(var + 1e-5f);
    }
}

// ---------------------------------------------------------------------------
// Fused GN + exact-GELU + depthwise 5x5 conv. Grid (6,6,16):
// block = 8x8 spatial tile x 64 channels; stage 12x12 halo (GN+GELU applied,
// zero-padded AFTER activation) in LDS (36.9 KB); conv from LDS, write Y.
// Lane owns channel c = t&63 -> coalesced global, conflict-free LDS.
// ---------------------------------------------------------------------------
__global__ __launch_bounds__(256) void gn_gelu_dwconv(
    const float* __restrict__ X, const float* __restrict__ st,
    const float* __restrict__ gg, const float* __restrict__ gb,
    const float* __restrict__ Kw, float* __restrict__ Y)
{
    __shared__ float tile[144][64];
    int h0 = blockIdx.x * 8, w0 = blockIdx.y * 8, c0 = blockIdx.z * 64;
    int t = threadIdx.x;
    int c = t & 63;
    int cg = (c0 + c) >> 5;
    float mu = st[2 * cg], rs = st[2 * cg + 1];
    float ga = gg[c0 + c], be = gb[c0 + c];

    for (int i = t; i < 144 * 64; i += 256) {
        int sp = i >> 6;                       // 0..143 (i&63 == c)
        int hy = h0 + (sp / 12) - 2, wx = w0 + (sp % 12) - 2;
        float v = 0.f;
        if (hy >= 0 && hy < HH && wx >= 0 && wx < WWW) {
            float x = X[(size_t)(hy * WWW + wx) * FF + c0 + c];
            x = (x - mu) * rs * ga + be;
            v = 0.5f * x * (1.f + erff(x * 0.70710678118654752f));
        }
        tile[sp][c] = v;
    }
    float kw[25];
    #pragma unroll
    for (int i = 0; i < 25; i++) kw[i] = Kw[(size_t)(c0 + c) * 25 + i];
    __syncthreads();

    int sgrp = t >> 6;                         // 0..3, 16 outputs each
    for (int s = 0; s < 16; s++) {
        int sp = sgrp * 16 + s;                // 0..63
        int oh = sp >> 3, ow = sp & 7;
        float acc = 0.f;
        #pragma unroll
        for (int ky = 0; ky < 5; ky++)
            #pragma unroll
            for (int kx = 0; kx < 5; kx++)
                acc += tile[(oh + ky) * 12 + ow + kx][c] * kw[ky * 5 + kx];
        Y[(size_t)((h0 + oh) * WWW + w0 + ow) * FF + c0 + c] = acc;
    }
}

// ---------------------------------------------------------------------------
extern "C" void kernel_launch(void* const* d_in, const int* in_sizes, int n_in,
                              void* d_out, int out_size, void* d_ws, size_t ws_size,
                              hipStream_t stream)
{
    (void)in_sizes;
    float* out = (float*)d_out;   // reference output dtype is float32

    if (n_in != 34) {
        diag_kernel<<<(out_size + 255) / 256, 256, 0, stream>>>(out, 2000.f, out_size);
        return;
    }

    const float* tgt    = (const float*)d_in[0];
    const float* gK     = (const float*)d_in[1];
    const float* gV     = (const float*)d_in[2];
    const float* lK     = (const float*)d_in[3];
    const float* lV     = (const float*)d_in[4];
    const float* ln1_g  = (const float*)d_in[5];
    const float* ln1_b  = (const float*)d_in[6];
    const float* ln2_g  = (const float*)d_in[7];
    const float* ln2_b  = (const float*)d_in[8];
    const float* ln3_g  = (const float*)d_in[9];
    const float* ln3_b  = (const float*)d_in[10];
    const float* ln4_g  = (const float*)d_in[11];
    const float* ln4_b  = (const float*)d_in[12];
    const float* sa_Wq  = (const float*)d_in[13];
    const float* sa_bq  = (const float*)d_in[14];
    const float* sa_Wk  = (const float*)d_in[15];
    const float* sa_bk  = (const float*)d_in[16];
    const float* sa_Wv  = (const float*)d_in[17];
    const float* sa_bv  = (const float*)d_in[18];
    const float* sa_Wo  = (const float*)d_in[19];
    const float* sa_bo  = (const float*)d_in[20];
    const float* Wq     = (const float*)d_in[21];
    const float* bq     = (const float*)d_in[22];
    const float* lt_Wo  = (const float*)d_in[23];
    const float* lt_bo  = (const float*)d_in[24];
    const float* st_Wo  = (const float*)d_in[25];
    const float* st_bo  = (const float*)d_in[26];
    const float* W1w    = (const float*)d_in[27];
    const float* b1w    = (const float*)d_in[28];
    const float* gn_g   = (const float*)d_in[29];
    const float* gn_b   = (const float*)d_in[30];
    const float* dw_k   = (const float*)d_in[31];
    const float* W2w    = (const float*)d_in[32];
    const float* b2w    = (const float*)d_in[33];

    // Workspace (fp32): t0..t5 [L,D] + X2 [L,FF] + ST.
    // bf16 attention buffers alias X2 (dead until the stage-3 conv):
    //   qb[LD] | kb1[2LD] | vtb1[2LD] | kb2[LD] | vtb2[LD] = 7*LD bf16 (8.26MB)
    // Attention split-K partials: OP = t0..t3 (4*LD fp32, contiguous, dead
    // during each attention); ML lives in X2 slack after the bf16 buffers.
    // gn_stats partials PS reuse the (dead in stage 3) ML slot.
    const size_t LD = (size_t)L * D;
    const size_t NEED = (6 * LD + (size_t)L * FF + 64) * 4;
    float* ws = (float*)d_ws;
    float* t0 = ws + 0 * LD;
    float* t1 = ws + 1 * LD;
    float* t2 = ws + 2 * LD;
    float* t3 = ws + 3 * LD;
    float* t4 = ws + 4 * LD;
    float* t5 = ws + 5 * LD;
    float* X1 = t0;                   // [L,FF], spans t0..t3 (dead in stage 3)
    float* X2 = ws + 6 * LD;          // [L,FF]
    float* ST = X2 + (size_t)L * FF;  // 64 floats
    bfraw* qb   = (bfraw*)X2;
    bfraw* kb1  = qb + LD;            // gK bf16 (2L)
    bfraw* vtb1 = qb + 3 * LD;        // gV^T bf16 (2L)
    bfraw* kb2  = qb + 5 * LD;        // self/st K bf16 (L)
    bfraw* vtb2 = qb + 6 * LD;        // self/st V^T bf16 (L)
    float* OP   = ws;                 // split-K partials: [SPL][L][D] = t0..t3
    float* ML   = X2 + (7 * LD) / 2;  // [SPL][NHD][L][2] = 590KB (slack: 1.18MB)
    float* PS   = ML;                 // gn_stats partials [32][RCH][2] (stage 3)

    if (ws_size < NEED) {
        int wsMiB = (int)(ws_size >> 20); if (wsMiB > 63) wsMiB = 63;
        diag_kernel<<<(out_size + 255) / 256, 256, 0, stream>>>(out, 64.f + (float)wsMiB, out_size);
        return;
    }

    const float scale = 0.17677669529663687f;  // 1/sqrt(32)
    dim3 gDD(L / 64, D / 64);         // (36, 4)
    dim3 gDF(L / 64, FF / 64);        // (36, 16)
    dim3 gATS(L / 16, NHD, SPL);      // (144, 8, 4), 64-thread blocks
    int  cvtLD  = (int)(LD / 1024);
    dim3 gT1(L / 32, NHD);
    dim3 gT2(2 * L / 32, NHD);
    dim3 gGN(32, RCH);                // gn_stats stage A
    dim3 gDW(6, 6, 16);               // fused gn+gelu+dwconv

    // ---- stage 1: self attention ----
    ln_kernel<<<L, 256, 0, stream>>>(tgt, nullptr, ln1_g, ln1_b, t0, nullptr);
    gemm_mfma<<<gDD, 256, 0, stream>>>(t0, sa_Wq, sa_bq, nullptr, t1, qb,  L, D, D);
    gemm_mfma<<<gDD, 256, 0, stream>>>(t0, sa_Wk, sa_bk, nullptr, t2, kb2, L, D, D);
    gemm_mfma<<<gDD, 256, 0, stream>>>(t0, sa_Wv, sa_bv, nullptr, t3, nullptr, L, D, D);
    cvtT_kernel<<<gT1, 256, 0, stream>>>(t3, vtb2, L);
    // t0..t3 now dead -> split-K partials
    attn_mfma_split<<<gATS, 64, 0, stream>>>(qb, kb2, vtb2, OP, ML, L, L / SPL, scale);
    attn_combine<<<L, 256, 0, stream>>>(OP, ML, t4);
    gemm_mfma<<<gDD, 256, 0, stream>>>(t4, sa_Wo, sa_bo, tgt, t5, nullptr, L, D, D); // t5 = tgt + SA

    // ---- stage 2: long-term + short-term cross-attention ----
    ln_kernel<<<L, 256, 0, stream>>>(t5, nullptr, ln2_g, ln2_b, t0, nullptr);          // curr_V
    gemm_mfma<<<gDD, 256, 0, stream>>>(t0, Wq, bq, nullptr, t1, qb, L, D, D);          // curr_Q
    ln_kernel<<<L, 256, 0, stream>>>(t1, lK, ln4_g, ln4_b, t2, kb2);                   // k_st (+bf16)
    ln_kernel<<<L, 256, 0, stream>>>(t0, lV, ln4_g, ln4_b, t3, nullptr);               // v_st
    cvtT_kernel<<<gT1, 256, 0, stream>>>(t3, vtb2, L);                                 // frees t3
    cvt_kernel<<<2 * cvtLD, 256, 0, stream>>>(gK, kb1);
    cvtT_kernel<<<gT2, 256, 0, stream>>>(gV, vtb1, 2 * L);
    // t0..t3 now dead -> split-K partials
    attn_mfma_split<<<gATS, 64, 0, stream>>>(qb, kb1, vtb1, OP, ML, 2 * L, 2 * L / SPL, scale);
    attn_combine<<<L, 256, 0, stream>>>(OP, ML, t4);
    gemm_mfma<<<gDD, 256, 0, stream>>>(t4, lt_Wo, lt_bo, t5, t5, nullptr, L, D, D);    // t5 += lt
    attn_mfma_split<<<gATS, 64, 0, stream>>>(qb, kb2, vtb2, OP, ML, L, L / SPL, scale);
    attn_combine<<<L, 256, 0, stream>>>(OP, ML, t4);
    gemm_mfma<<<gDD, 256, 0, stream>>>(t4, st_Wo, st_bo, t5, t5, nullptr, L, D, D);    // t5 += st

    // ---- stage 3: FFN with fused GN + GELU + depthwise conv ----
    ln_kernel<<<L, 256, 0, stream>>>(t5, nullptr, ln3_g, ln3_b, t4, nullptr);          // ln3 (outside X1)
    gemm_mfma<<<gDF, 256, 0, stream>>>(t4, W1w, b1w, nullptr, X1, nullptr, L, FF, D);
    gn_stats_part<<<gGN, 256, 0, stream>>>(X1, PS);
    gn_stats_final<<<1, 64, 0, stream>>>(PS, ST);
    gn_gelu_dwconv<<<gDW, 256, 0, stream>>>(X1, ST, gn_g, gn_b, dw_k, X2);             // X2 = conv out
    gemm_mfma<<<gDD, 256, 0, stream>>>(X2, W2w, b2w, t5, out, nullptr, L, D, FF);      // out = t5 + FFN
}

// Round 4
// 363.444 us; speedup vs baseline: 1.7005x; 1.1038x over previous
//
#include <hip/hip_runtime.h>
#include <hip/hip_bf16.h>

#define L   2304
#define D   256
#define NHD 8
#define HD  32
#define FF  1024
#define HH  48
#define WWW 48
#define SPL 4     // attention split-K factor
#define RCH 24    // gn_stats row chunks
#define RP  (L / RCH)   // 96 rows per chunk

typedef unsigned short bfraw;
typedef __attribute__((ext_vector_type(8))) short s8v;   // 8 bf16 = 4 VGPRs
typedef __attribute__((ext_vector_type(4))) float f4v;   // MFMA C/D frag

__device__ __forceinline__ bfraw f2b(float x) {
    __hip_bfloat16 h = __float2bfloat16(x);
    return __builtin_bit_cast(bfraw, h);
}

// Diagnostic: fill output with a constant (decodable from reported absmax).
__global__ __launch_bounds__(256) void diag_kernel(float* __restrict__ out, float c, int n)
{
    int i = blockIdx.x * 256 + threadIdx.x;
    if (i < n) out[i] = c;
}

// ---------------------------------------------------------------------------
// LayerNorm over D=256, fp32 (+ optional bf16 secondary output).
// ---------------------------------------------------------------------------
__global__ __launch_bounds__(256) void ln_kernel(
    const float* __restrict__ inA, const float* __restrict__ inB,
    const float* __restrict__ g, const float* __restrict__ b,
    float* __restrict__ out, bfraw* __restrict__ outb)
{
    int row = blockIdx.x, t = threadIdx.x;
    size_t idx = (size_t)row * D + t;
    float v = inA[idx];
    if (inB) v += inB[idx];
    __shared__ float rs[256], rq[256];
    rs[t] = v; rq[t] = v * v;
    __syncthreads();
    for (int o = 128; o > 0; o >>= 1) {
        if (t < o) { rs[t] += rs[t + o]; rq[t] += rq[t + o]; }
        __syncthreads();
    }
    float mean = rs[0] * (1.f / D);
    float var  = rq[0] * (1.f / D) - mean * mean;
    float rstd = rsqrtf(var + 1e-5f);
    float r = (v - mean) * rstd * g[t] + b[t];
    out[idx] = r;
    if (outb) outb[idx] = f2b(r);
}

// ---------------------------------------------------------------------------
// MFMA bf16 GEMM: C[M,N] = A[M,K] @ W[N,K]^T + bias (+res), fp32 in/out.
// 32x64 tile, 4 waves: wave w -> rows (w&1)*16, cols (w>>1)*32 (2 j-frags).
// BK=32, mfma_f32_16x16x32_bf16, fp32 accumulate. A/W converted to bf16
// in-register during LDS staging; XOR swizzle (16B group g ^= (row>>2)&3).
// Grid (M/32, N/64) -- doubles block count vs 64x64 (fills 256 CUs).
// ---------------------------------------------------------------------------
__global__ __launch_bounds__(256) void gemm_mfma(
    const float* __restrict__ A, const float* __restrict__ W,
    const float* __restrict__ bias, const float* res, float* out,
    bfraw* __restrict__ outb,
    int M, int N, int K)
{
    __shared__ __attribute__((aligned(16))) short Al[32][32];
    __shared__ __attribute__((aligned(16))) short Wl[64][32];
    int t = threadIdx.x;
    int w = t >> 6, l = t & 63;
    int lo = l & 15, quad = l >> 4;
    int m0 = blockIdx.x * 32, n0 = blockIdx.y * 64;
    int wr = (w & 1) * 16, wc = (w >> 1) * 32;
    f4v acc[2];
    acc[0] = (f4v){0.f, 0.f, 0.f, 0.f};
    acc[1] = (f4v){0.f, 0.f, 0.f, 0.f};

    int aswz = (quad ^ ((lo >> 2) & 3)) * 8;   // swizzled k-group for frag reads
    int arow = t >> 3, apart = t & 7;          // staging: row x 8 fp32-quads
    int acol = ((apart >> 1) ^ ((arow >> 2) & 3)) * 8 + (apart & 1) * 4;

    for (int k0 = 0; k0 < K; k0 += 32) {
        float4 a4 = *reinterpret_cast<const float4*>(A + (size_t)(m0 + arow) * K + k0 + apart * 4);
        float4 w4[2];
        #pragma unroll
        for (int i = 0; i < 2; i++) {
            int row = i * 32 + arow;
            w4[i] = *reinterpret_cast<const float4*>(W + (size_t)(n0 + row) * K + k0 + apart * 4);
        }
        __syncthreads();
        {
            ushort4 ab;
            ab.x = f2b(a4.x); ab.y = f2b(a4.y); ab.z = f2b(a4.z); ab.w = f2b(a4.w);
            *reinterpret_cast<ushort4*>(&Al[arow][acol]) = ab;
            #pragma unroll
            for (int i = 0; i < 2; i++) {
                int row = i * 32 + arow;
                int col = ((apart >> 1) ^ ((row >> 2) & 3)) * 8 + (apart & 1) * 4;
                ushort4 wb;
                wb.x = f2b(w4[i].x); wb.y = f2b(w4[i].y); wb.z = f2b(w4[i].z); wb.w = f2b(w4[i].w);
                *reinterpret_cast<ushort4*>(&Wl[row][col]) = wb;
            }
        }
        __syncthreads();
        s8v af = *reinterpret_cast<const s8v*>(&Al[wr + lo][aswz]);
        #pragma unroll
        for (int j = 0; j < 2; j++) {
            s8v wf = *reinterpret_cast<const s8v*>(&Wl[wc + j * 16 + lo][aswz]);
            acc[j] = __builtin_amdgcn_mfma_f32_16x16x32_bf16(af, wf, acc[j], 0, 0, 0);
        }
    }

    #pragma unroll
    for (int j = 0; j < 2; j++) {
        #pragma unroll
        for (int r = 0; r < 4; r++) {
            int mrow = m0 + wr + quad * 4 + r;
            int ncol = n0 + wc + j * 16 + lo;
            float v = acc[j][r] + bias[ncol];
            size_t idx = (size_t)mrow * N + ncol;
            if (res) v += res[idx];
            out[idx] = v;
            if (outb) outb[idx] = f2b(v);
        }
    }
}

// fp32 [n] -> bf16 [n], vectorized (n % 1024 == 0).
__global__ __launch_bounds__(256) void cvt_kernel(
    const float* __restrict__ in, bfraw* __restrict__ out)
{
    size_t i = ((size_t)blockIdx.x * 256 + threadIdx.x) * 4;
    float4 v = *reinterpret_cast<const float4*>(in + i);
    ushort4 o;
    o.x = f2b(v.x); o.y = f2b(v.y); o.z = f2b(v.z); o.w = f2b(v.w);
    *reinterpret_cast<ushort4*>(out + i) = o;
}

// fp32 [N][D] -> bf16 [NH][HD][N] (transposed per head). Grid (N/32, NH).
__global__ __launch_bounds__(256) void cvtT_kernel(
    const float* __restrict__ in, bfraw* __restrict__ out, int N)
{
    __shared__ float Ls[32][33];
    int h = blockIdx.y, n0 = blockIdx.x * 32, t = threadIdx.x;
    int nl = t >> 3, dq = t & 7;
    float4 v = *reinterpret_cast<const float4*>(in + (size_t)(n0 + nl) * D + h * HD + dq * 4);
    Ls[nl][dq*4+0] = v.x; Ls[nl][dq*4+1] = v.y;
    Ls[nl][dq*4+2] = v.z; Ls[nl][dq*4+3] = v.w;
    __syncthreads();
    int dl = t >> 3, nq = t & 7;
    ushort4 o;
    o.x = f2b(Ls[nq*4+0][dl]); o.y = f2b(Ls[nq*4+1][dl]);
    o.z = f2b(Ls[nq*4+2][dl]); o.w = f2b(Ls[nq*4+3][dl]);
    *reinterpret_cast<ushort4*>(out + (size_t)(h * HD + dl) * N + n0 + nq * 4) = o;
}

// ---------------------------------------------------------------------------
// MFMA flash attention, split-K, 4 waves sharing K/V staging.
// Grid (L/64, NHD, SPL); 256 threads. Wave w owns q-tile q0 = bx*64 + w*16;
// all 4 waves share the Ks/Vts tiles (1 global s8v load each per 64-key
// step instead of 8 -> 4x less staging + 4x less L2 traffic). Per-wave
// math identical to the verified single-wave kernel; Ps is per-wave.
// Staging loads issued BEFORE the barrier to hide HBM latency.
// ---------------------------------------------------------------------------
__global__ __launch_bounds__(256) void attn_mfma_split(
    const bfraw* __restrict__ Qb, const bfraw* __restrict__ Kb,
    const bfraw* __restrict__ Vt, float* __restrict__ OP,
    float* __restrict__ ML, int Lk, int chunk, float scale)
{
    __shared__ __attribute__((aligned(16))) short Ks[64][32];
    __shared__ __attribute__((aligned(16))) short Vts[32][72];
    __shared__ __attribute__((aligned(16))) short Ps[4][16][72];
    int t = threadIdx.x;
    int w = t >> 6, l = t & 63;
    int h = blockIdx.y, q0 = blockIdx.x * 64 + w * 16, z = blockIdx.z;
    int lo = l & 15, quad = l >> 4;
    int kb = z * chunk, ke = kb + chunk;

    s8v qf = *reinterpret_cast<const s8v*>(Qb + (size_t)(q0 + lo) * D + h * HD + quad * 8);
    int kswz = (quad ^ ((lo >> 2) & 3)) * 8;   // swizzled k-frag group

    // shared staging: thread t loads one s8v of K and one of V per step
    int skey = t >> 2, spart = t & 3;
    int kcol = (spart ^ ((skey >> 2) & 3)) * 8;
    int sd = t >> 3, svp = t & 7;
    const bfraw* kp = Kb + (size_t)skey * D + h * HD + spart * 8;
    const bfraw* vp = Vt + (size_t)(h * HD + sd) * Lk + svp * 8;

    float m_r = -1e30f, l_r = 0.f;
    f4v o0 = {0.f, 0.f, 0.f, 0.f}, o1 = {0.f, 0.f, 0.f, 0.f};

    for (int k0 = kb; k0 < ke; k0 += 64) {
        s8v kv = *reinterpret_cast<const s8v*>(kp + (size_t)k0 * D);
        s8v vv = *reinterpret_cast<const s8v*>(vp + k0);
        __syncthreads();   // all waves done reading prev tile
        *reinterpret_cast<s8v*>(&Ks[skey][kcol]) = kv;
        *reinterpret_cast<s8v*>(&Vts[sd][svp * 8]) = vv;
        __syncthreads();   // staged data visible

        f4v sc4[4];
        #pragma unroll
        for (int s = 0; s < 4; s++) {
            s8v kf = *reinterpret_cast<const s8v*>(&Ks[lo + 16 * s][kswz]);
            sc4[s] = __builtin_amdgcn_mfma_f32_16x16x32_bf16(kf, qf, (f4v){0.f,0.f,0.f,0.f}, 0, 0, 0);
        }
        float cm = -1e30f;
        #pragma unroll
        for (int s = 0; s < 4; s++)
            #pragma unroll
            for (int r = 0; r < 4; r++) {
                sc4[s][r] *= scale;
                cm = fmaxf(cm, sc4[s][r]);
            }
        cm = fmaxf(cm, __shfl_xor(cm, 16));
        cm = fmaxf(cm, __shfl_xor(cm, 32));
        float mnew = fmaxf(m_r, cm);
        float alpha = __expf(m_r - mnew);
        float ls = 0.f;
        #pragma unroll
        for (int s = 0; s < 4; s++) {
            float p0 = __expf(sc4[s][0] - mnew), p1 = __expf(sc4[s][1] - mnew);
            float p2 = __expf(sc4[s][2] - mnew), p3 = __expf(sc4[s][3] - mnew);
            ls += p0 + p1 + p2 + p3;
            ushort4 pk;
            pk.x = f2b(p0); pk.y = f2b(p1); pk.z = f2b(p2); pk.w = f2b(p3);
            *reinterpret_cast<ushort4*>(&Ps[w][lo][s * 16 + quad * 4]) = pk;
        }
        ls += __shfl_xor(ls, 16);
        ls += __shfl_xor(ls, 32);
        l_r = l_r * alpha + ls;
        m_r = mnew;
        #pragma unroll
        for (int r = 0; r < 4; r++) {
            float a = __shfl(alpha, quad * 4 + r);
            o0[r] *= a; o1[r] *= a;
        }
        #pragma unroll
        for (int kc = 0; kc < 2; kc++) {
            s8v pf = *reinterpret_cast<const s8v*>(&Ps[w][lo][kc * 32 + quad * 8]);
            s8v v0 = *reinterpret_cast<const s8v*>(&Vts[lo][kc * 32 + quad * 8]);
            s8v v1 = *reinterpret_cast<const s8v*>(&Vts[16 + lo][kc * 32 + quad * 8]);
            o0 = __builtin_amdgcn_mfma_f32_16x16x32_bf16(pf, v0, o0, 0, 0, 0);
            o1 = __builtin_amdgcn_mfma_f32_16x16x32_bf16(pf, v1, o1, 0, 0, 0);
        }
    }

    float* Oz = OP + (size_t)z * L * D;
    #pragma unroll
    for (int r = 0; r < 4; r++) {
        int qg = q0 + quad * 4 + r;
        Oz[(size_t)qg * D + h * HD + lo]      = o0[r];   // unnormalized
        Oz[(size_t)qg * D + h * HD + 16 + lo] = o1[r];
    }
    if (l < 16) {
        size_t mi = (((size_t)z * NHD + h) * L + q0 + lo) * 2;
        ML[mi]     = m_r;
        ML[mi + 1] = l_r;
    }
}

// Merge SPL split-K partials: exact online-softmax combine.
// Grid (L), 256 threads; thread t handles head t>>5, dim t&31.
__global__ __launch_bounds__(256) void attn_combine(
    const float* __restrict__ OP, const float* __restrict__ ML,
    float* __restrict__ O)
{
    int q = blockIdx.x, t = threadIdx.x, h = t >> 5;
    float m[SPL], lv[SPL];
    float M = -1e30f;
    #pragma unroll
    for (int s = 0; s < SPL; s++) {
        size_t mi = (((size_t)s * NHD + h) * L + q) * 2;
        m[s]  = ML[mi];
        lv[s] = ML[mi + 1];
        M = fmaxf(M, m[s]);
    }
    float wl = 0.f, acc = 0.f;
    #pragma unroll
    for (int s = 0; s < SPL; s++) {
        float w = __expf(m[s] - M);
        wl  += w * lv[s];
        acc += w * OP[(size_t)s * L * D + (size_t)q * D + t];
    }
    O[(size_t)q * D + t] = acc / wl;
}

// ---------------------------------------------------------------------------
// GroupNorm stats, two-stage. Stage A: grid (32, RCH); each block reduces a
// 96-row x 32-col slab of X [L, FF] to partial (sum, sumsq) in ps.
// ---------------------------------------------------------------------------
__global__ __launch_bounds__(256) void gn_stats_part(
    const float* __restrict__ X, float* __restrict__ ps)
{
    int g = blockIdx.x, rc = blockIdx.y, t = threadIdx.x;
    int cq = (t & 7) * 4;            // col quad within group (0..28)
    int rl = t >> 3;                 // 0..31 row lane
    int r0 = rc * RP;
    float s = 0.f, sq = 0.f;
    #pragma unroll
    for (int p = 0; p < RP / 32; p++) {
        int l = r0 + p * 32 + rl;
        float4 v = *reinterpret_cast<const float4*>(X + (size_t)l * FF + g * 32 + cq);
        s  += v.x + v.y + v.z + v.w;
        sq += v.x*v.x + v.y*v.y + v.z*v.z + v.w*v.w;
    }
    __shared__ float rs[256], rq[256];
    rs[t] = s; rq[t] = sq;
    __syncthreads();
    for (int o = 128; o > 0; o >>= 1) {
        if (t < o) { rs[t] += rs[t + o]; rq[t] += rq[t + o]; }
        __syncthreads();
    }
    if (t == 0) {
        ps[(g * RCH + rc) * 2]     = rs[0];
        ps[(g * RCH + rc) * 2 + 1] = rq[0];
    }
}

// Stage B: one block; thread g<32 folds RCH partials into mean/rstd.
__global__ __launch_bounds__(64) void gn_stats_final(
    const float* __restrict__ ps, float* __restrict__ st)
{
    int g = threadIdx.x;
    if (g < 32) {
        float s = 0.f, sq = 0.f;
        for (int i = 0; i < RCH; i++) {
            s  += ps[(g * RCH + i) * 2];
            sq += ps[(g * RCH + i) * 2 + 1];
        }
        float n = (float)(L * 32);
        float mean = s / n;
        float var  = sq / n - mean * mean;
        st[g * 2]     = mean;
        st[g * 2 + 1] = rsqrtf(var + 1e-5f);
    }
}

// ---------------------------------------------------------------------------
// Fused GN + exact-GELU + depthwise 5x5 conv. Grid (6,6,16):
// block = 8x8 spatial tile x 64 channels; stage 12x12 halo (GN+GELU applied,
// zero-padded AFTER activation) in LDS (36.9 KB); conv from LDS, write Y.
// Lane owns channel c = t&63 -> coalesced global, conflict-free LDS.
// ---------------------------------------------------------------------------
__global__ __launch_bounds__(256) void gn_gelu_dwconv(
    const float* __restrict__ X, const float* __restrict__ st,
    const float* __restrict__ gg, const float* __restrict__ gb,
    const float* __restrict__ Kw, float* __restrict__ Y)
{
    __shared__ float tile[144][64];
    int h0 = blockIdx.x * 8, w0 = blockIdx.y * 8, c0 = blockIdx.z * 64;
    int t = threadIdx.x;
    int c = t & 63;
    int cg = (c0 + c) >> 5;
    float mu = st[2 * cg], rs = st[2 * cg + 1];
    float ga = gg[c0 + c], be = gb[c0 + c];

    for (int i = t; i < 144 * 64; i += 256) {
        int sp = i >> 6;                       // 0..143 (i&63 == c)
        int hy = h0 + (sp / 12) - 2, wx = w0 + (sp % 12) - 2;
        float v = 0.f;
        if (hy >= 0 && hy < HH && wx >= 0 && wx < WWW) {
            float x = X[(size_t)(hy * WWW + wx) * FF + c0 + c];
            x = (x - mu) * rs * ga + be;
            v = 0.5f * x * (1.f + erff(x * 0.70710678118654752f));
        }
        tile[sp][c] = v;
    }
    float kw[25];
    #pragma unroll
    for (int i = 0; i < 25; i++) kw[i] = Kw[(size_t)(c0 + c) * 25 + i];
    __syncthreads();

    int sgrp = t >> 6;                         // 0..3, 16 outputs each
    for (int s = 0; s < 16; s++) {
        int sp = sgrp * 16 + s;                // 0..63
        int oh = sp >> 3, ow = sp & 7;
        float acc = 0.f;
        #pragma unroll
        for (int ky = 0; ky < 5; ky++)
            #pragma unroll
            for (int kx = 0; kx < 5; kx++)
                acc += tile[(oh + ky) * 12 + ow + kx][c] * kw[ky * 5 + kx];
        Y[(size_t)((h0 + oh) * WWW + w0 + ow) * FF + c0 + c] = acc;
    }
}

// ---------------------------------------------------------------------------
extern "C" void kernel_launch(void* const* d_in, const int* in_sizes, int n_in,
                              void* d_out, int out_size, void* d_ws, size_t ws_size,
                              hipStream_t stream)
{
    (void)in_sizes;
    float* out = (float*)d_out;   // reference output dtype is float32

    if (n_in != 34) {
        diag_kernel<<<(out_size + 255) / 256, 256, 0, stream>>>(out, 2000.f, out_size);
        return;
    }

    const float* tgt    = (const float*)d_in[0];
    const float* gK     = (const float*)d_in[1];
    const float* gV     = (const float*)d_in[2];
    const float* lK     = (const float*)d_in[3];
    const float* lV     = (const float*)d_in[4];
    const float* ln1_g  = (const float*)d_in[5];
    const float* ln1_b  = (const float*)d_in[6];
    const float* ln2_g  = (const float*)d_in[7];
    const float* ln2_b  = (const float*)d_in[8];
    const float* ln3_g  = (const float*)d_in[9];
    const float* ln3_b  = (const float*)d_in[10];
    const float* ln4_g  = (const float*)d_in[11];
    const float* ln4_b  = (const float*)d_in[12];
    const float* sa_Wq  = (const float*)d_in[13];
    const float* sa_bq  = (const float*)d_in[14];
    const float* sa_Wk  = (const float*)d_in[15];
    const float* sa_bk  = (const float*)d_in[16];
    const float* sa_Wv  = (const float*)d_in[17];
    const float* sa_bv  = (const float*)d_in[18];
    const float* sa_Wo  = (const float*)d_in[19];
    const float* sa_bo  = (const float*)d_in[20];
    const float* Wq     = (const float*)d_in[21];
    const float* bq     = (const float*)d_in[22];
    const float* lt_Wo  = (const float*)d_in[23];
    const float* lt_bo  = (const float*)d_in[24];
    const float* st_Wo  = (const float*)d_in[25];
    const float* st_bo  = (const float*)d_in[26];
    const float* W1w    = (const float*)d_in[27];
    const float* b1w    = (const float*)d_in[28];
    const float* gn_g   = (const float*)d_in[29];
    const float* gn_b   = (const float*)d_in[30];
    const float* dw_k   = (const float*)d_in[31];
    const float* W2w    = (const float*)d_in[32];
    const float* b2w    = (const float*)d_in[33];

    // Workspace (fp32): t0..t5 [L,D] + X2 [L,FF] + ST.
    // bf16 attention buffers alias X2 (dead until the stage-3 conv):
    //   qb[LD] | kb1[2LD] | vtb1[2LD] | kb2[LD] | vtb2[LD] = 7*LD bf16 (8.26MB)
    // Attention split-K partials: OP = t0..t3 (4*LD fp32, contiguous, dead
    // during each attention); ML lives in X2 slack after the bf16 buffers.
    // gn_stats partials PS reuse the (dead in stage 3) ML slot.
    const size_t LD = (size_t)L * D;
    const size_t NEED = (6 * LD + (size_t)L * FF + 64) * 4;
    float* ws = (float*)d_ws;
    float* t0 = ws + 0 * LD;
    float* t1 = ws + 1 * LD;
    float* t2 = ws + 2 * LD;
    float* t3 = ws + 3 * LD;
    float* t4 = ws + 4 * LD;
    float* t5 = ws + 5 * LD;
    float* X1 = t0;                   // [L,FF], spans t0..t3 (dead in stage 3)
    float* X2 = ws + 6 * LD;          // [L,FF]
    float* ST = X2 + (size_t)L * FF;  // 64 floats
    bfraw* qb   = (bfraw*)X2;
    bfraw* kb1  = qb + LD;            // gK bf16 (2L)
    bfraw* vtb1 = qb + 3 * LD;        // gV^T bf16 (2L)
    bfraw* kb2  = qb + 5 * LD;        // self/st K bf16 (L)
    bfraw* vtb2 = qb + 6 * LD;        // self/st V^T bf16 (L)
    float* OP   = ws;                 // split-K partials: [SPL][L][D] = t0..t3
    float* ML   = X2 + (7 * LD) / 2;  // [SPL][NHD][L][2] = 590KB (slack: 1.18MB)
    float* PS   = ML;                 // gn_stats partials [32][RCH][2] (stage 3)

    if (ws_size < NEED) {
        int wsMiB = (int)(ws_size >> 20); if (wsMiB > 63) wsMiB = 63;
        diag_kernel<<<(out_size + 255) / 256, 256, 0, stream>>>(out, 64.f + (float)wsMiB, out_size);
        return;
    }

    const float scale = 0.17677669529663687f;  // 1/sqrt(32)
    dim3 gDD(L / 32, D / 64);         // (72, 4)
    dim3 gDF(L / 32, FF / 64);        // (72, 16)
    dim3 gATS(L / 64, NHD, SPL);      // (36, 8, 4), 256-thread blocks
    int  cvtLD  = (int)(LD / 1024);
    dim3 gT1(L / 32, NHD);
    dim3 gT2(2 * L / 32, NHD);
    dim3 gGN(32, RCH);                // gn_stats stage A
    dim3 gDW(6, 6, 16);               // fused gn+gelu+dwconv

    // ---- stage 1: self attention ----
    ln_kernel<<<L, 256, 0, stream>>>(tgt, nullptr, ln1_g, ln1_b, t0, nullptr);
    gemm_mfma<<<gDD, 256, 0, stream>>>(t0, sa_Wq, sa_bq, nullptr, t1, qb,  L, D, D);
    gemm_mfma<<<gDD, 256, 0, stream>>>(t0, sa_Wk, sa_bk, nullptr, t2, kb2, L, D, D);
    gemm_mfma<<<gDD, 256, 0, stream>>>(t0, sa_Wv, sa_bv, nullptr, t3, nullptr, L, D, D);
    cvtT_kernel<<<gT1, 256, 0, stream>>>(t3, vtb2, L);
    // t0..t3 now dead -> split-K partials
    attn_mfma_split<<<gATS, 256, 0, stream>>>(qb, kb2, vtb2, OP, ML, L, L / SPL, scale);
    attn_combine<<<L, 256, 0, stream>>>(OP, ML, t4);
    gemm_mfma<<<gDD, 256, 0, stream>>>(t4, sa_Wo, sa_bo, tgt, t5, nullptr, L, D, D); // t5 = tgt + SA

    // ---- stage 2: long-term + short-term cross-attention ----
    ln_kernel<<<L, 256, 0, stream>>>(t5, nullptr, ln2_g, ln2_b, t0, nullptr);          // curr_V
    gemm_mfma<<<gDD, 256, 0, stream>>>(t0, Wq, bq, nullptr, t1, qb, L, D, D);          // curr_Q
    ln_kernel<<<L, 256, 0, stream>>>(t1, lK, ln4_g, ln4_b, t2, kb2);                   // k_st (+bf16)
    ln_kernel<<<L, 256, 0, stream>>>(t0, lV, ln4_g, ln4_b, t3, nullptr);               // v_st
    cvtT_kernel<<<gT1, 256, 0, stream>>>(t3, vtb2, L);                                 // frees t3
    cvt_kernel<<<2 * cvtLD, 256, 0, stream>>>(gK, kb1);
    cvtT_kernel<<<gT2, 256, 0, stream>>>(gV, vtb1, 2 * L);
    // t0..t3 now dead -> split-K partials
    attn_mfma_split<<<gATS, 256, 0, stream>>>(qb, kb1, vtb1, OP, ML, 2 * L, 2 * L / SPL, scale);
    attn_combine<<<L, 256, 0, stream>>>(OP, ML, t4);
    gemm_mfma<<<gDD, 256, 0, stream>>>(t4, lt_Wo, lt_bo, t5, t5, nullptr, L, D, D);    // t5 += lt
    attn_mfma_split<<<gATS, 256, 0, stream>>>(qb, kb2, vtb2, OP, ML, L, L / SPL, scale);
    attn_combine<<<L, 256, 0, stream>>>(OP, ML, t4);
    gemm_mfma<<<gDD, 256, 0, stream>>>(t4, st_Wo, st_bo, t5, t5, nullptr, L, D, D);    // t5 += st

    // ---- stage 3: FFN with fused GN + GELU + depthwise conv ----
    ln_kernel<<<L, 256, 0, stream>>>(t5, nullptr, ln3_g, ln3_b, t4, nullptr);          // ln3 (outside X1)
    gemm_mfma<<<gDF, 256, 0, stream>>>(t4, W1w, b1w, nullptr, X1, nullptr, L, FF, D);
    gn_stats_part<<<gGN, 256, 0, stream>>>(X1, PS);
    gn_stats_final<<<1, 64, 0, stream>>>(PS, ST);
    gn_gelu_dwconv<<<gDW, 256, 0, stream>>>(X1, ST, gn_g, gn_b, dw_k, X2);             // X2 = conv out
    gemm_mfma<<<gDD, 256, 0, stream>>>(X2, W2w, b2w, t5, out, nullptr, L, D, FF);      // out = t5 + FFN
}

// Round 5
// 348.342 us; speedup vs baseline: 1.7742x; 1.0434x over previous
//
#include <hip/hip_runtime.h>
#include <hip/hip_bf16.h>

#define L   2304
#define D   256
#define NHD 8
#define HD  32
#define FF  1024
#define HH  48
#define WWW 48
#define SPL 4     // attention split-K factor
#define RCH 24    // gn_stats row chunks
#define RP  (L / RCH)   // 96 rows per chunk
#define S2LOG 0.25503486f   // log2(e)/sqrt(32): folded into Q bf16 copy

typedef unsigned short bfraw;
typedef __attribute__((ext_vector_type(8))) short s8v;   // 8 bf16 = 4 VGPRs
typedef __attribute__((ext_vector_type(4))) float f4v;   // MFMA C/D frag

__device__ __forceinline__ bfraw f2b(float x) {
    __hip_bfloat16 h = __float2bfloat16(x);
    return __builtin_bit_cast(bfraw, h);
}

// Diagnostic: fill output with a constant (decodable from reported absmax).
__global__ __launch_bounds__(256) void diag_kernel(float* __restrict__ out, float c, int n)
{
    int i = blockIdx.x * 256 + threadIdx.x;
    if (i < n) out[i] = c;
}

// ---------------------------------------------------------------------------
// LayerNorm over D=256, fp32 (+ optional bf16 secondary output).
// ---------------------------------------------------------------------------
__global__ __launch_bounds__(256) void ln_kernel(
    const float* __restrict__ inA, const float* __restrict__ inB,
    const float* __restrict__ g, const float* __restrict__ b,
    float* __restrict__ out, bfraw* __restrict__ outb)
{
    int row = blockIdx.x, t = threadIdx.x;
    size_t idx = (size_t)row * D + t;
    float v = inA[idx];
    if (inB) v += inB[idx];
    __shared__ float rs[256], rq[256];
    rs[t] = v; rq[t] = v * v;
    __syncthreads();
    for (int o = 128; o > 0; o >>= 1) {
        if (t < o) { rs[t] += rs[t + o]; rq[t] += rq[t + o]; }
        __syncthreads();
    }
    float mean = rs[0] * (1.f / D);
    float var  = rq[0] * (1.f / D) - mean * mean;
    float rstd = rsqrtf(var + 1e-5f);
    float r = (v - mean) * rstd * g[t] + b[t];
    out[idx] = r;
    if (outb) outb[idx] = f2b(r);
}

// ---------------------------------------------------------------------------
// MFMA bf16 GEMM: C[M,N] = A[M,K] @ W[N,K]^T + bias (+res), fp32 in/out.
// 32x64 tile, 4 waves. BK=32, mfma_f32_16x16x32_bf16, fp32 accumulate.
// XOR swizzle (16B group g ^= (row>>2)&3). Optional bf16 secondary output
// outb scaled by oscale (fp32 out is NEVER scaled).
// ---------------------------------------------------------------------------
__global__ __launch_bounds__(256) void gemm_mfma(
    const float* __restrict__ A, const float* __restrict__ W,
    const float* __restrict__ bias, const float* res, float* out,
    bfraw* __restrict__ outb, float oscale,
    int M, int N, int K)
{
    __shared__ __attribute__((aligned(16))) short Al[32][32];
    __shared__ __attribute__((aligned(16))) short Wl[64][32];
    int t = threadIdx.x;
    int w = t >> 6, l = t & 63;
    int lo = l & 15, quad = l >> 4;
    int m0 = blockIdx.x * 32, n0 = blockIdx.y * 64;
    int wr = (w & 1) * 16, wc = (w >> 1) * 32;
    f4v acc[2];
    acc[0] = (f4v){0.f, 0.f, 0.f, 0.f};
    acc[1] = (f4v){0.f, 0.f, 0.f, 0.f};

    int aswz = (quad ^ ((lo >> 2) & 3)) * 8;   // swizzled k-group for frag reads
    int arow = t >> 3, apart = t & 7;          // staging: row x 8 fp32-quads
    int acol = ((apart >> 1) ^ ((arow >> 2) & 3)) * 8 + (apart & 1) * 4;

    for (int k0 = 0; k0 < K; k0 += 32) {
        float4 a4 = *reinterpret_cast<const float4*>(A + (size_t)(m0 + arow) * K + k0 + apart * 4);
        float4 w4[2];
        #pragma unroll
        for (int i = 0; i < 2; i++) {
            int row = i * 32 + arow;
            w4[i] = *reinterpret_cast<const float4*>(W + (size_t)(n0 + row) * K + k0 + apart * 4);
        }
        __syncthreads();
        {
            ushort4 ab;
            ab.x = f2b(a4.x); ab.y = f2b(a4.y); ab.z = f2b(a4.z); ab.w = f2b(a4.w);
            *reinterpret_cast<ushort4*>(&Al[arow][acol]) = ab;
            #pragma unroll
            for (int i = 0; i < 2; i++) {
                int row = i * 32 + arow;
                int col = ((apart >> 1) ^ ((row >> 2) & 3)) * 8 + (apart & 1) * 4;
                ushort4 wb;
                wb.x = f2b(w4[i].x); wb.y = f2b(w4[i].y); wb.z = f2b(w4[i].z); wb.w = f2b(w4[i].w);
                *reinterpret_cast<ushort4*>(&Wl[row][col]) = wb;
            }
        }
        __syncthreads();
        s8v af = *reinterpret_cast<const s8v*>(&Al[wr + lo][aswz]);
        #pragma unroll
        for (int j = 0; j < 2; j++) {
            s8v wf = *reinterpret_cast<const s8v*>(&Wl[wc + j * 16 + lo][aswz]);
            acc[j] = __builtin_amdgcn_mfma_f32_16x16x32_bf16(af, wf, acc[j], 0, 0, 0);
        }
    }

    #pragma unroll
    for (int j = 0; j < 2; j++) {
        #pragma unroll
        for (int r = 0; r < 4; r++) {
            int mrow = m0 + wr + quad * 4 + r;
            int ncol = n0 + wc + j * 16 + lo;
            float v = acc[j][r] + bias[ncol];
            size_t idx = (size_t)mrow * N + ncol;
            if (res) v += res[idx];
            out[idx] = v;
            if (outb) outb[idx] = f2b(v * oscale);
        }
    }
}

// fp32 [n] -> bf16 [n], vectorized (n % 1024 == 0).
__global__ __launch_bounds__(256) void cvt_kernel(
    const float* __restrict__ in, bfraw* __restrict__ out)
{
    size_t i = ((size_t)blockIdx.x * 256 + threadIdx.x) * 4;
    float4 v = *reinterpret_cast<const float4*>(in + i);
    ushort4 o;
    o.x = f2b(v.x); o.y = f2b(v.y); o.z = f2b(v.z); o.w = f2b(v.w);
    *reinterpret_cast<ushort4*>(out + i) = o;
}

// fp32 [N][D] -> bf16 [NH][HD][N] (transposed per head). Grid (N/32, NH).
__global__ __launch_bounds__(256) void cvtT_kernel(
    const float* __restrict__ in, bfraw* __restrict__ out, int N)
{
    __shared__ float Ls[32][33];
    int h = blockIdx.y, n0 = blockIdx.x * 32, t = threadIdx.x;
    int nl = t >> 3, dq = t & 7;
    float4 v = *reinterpret_cast<const float4*>(in + (size_t)(n0 + nl) * D + h * HD + dq * 4);
    Ls[nl][dq*4+0] = v.x; Ls[nl][dq*4+1] = v.y;
    Ls[nl][dq*4+2] = v.z; Ls[nl][dq*4+3] = v.w;
    __syncthreads();
    int dl = t >> 3, nq = t & 7;
    ushort4 o;
    o.x = f2b(Ls[nq*4+0][dl]); o.y = f2b(Ls[nq*4+1][dl]);
    o.z = f2b(Ls[nq*4+2][dl]); o.w = f2b(Ls[nq*4+3][dl]);
    *reinterpret_cast<ushort4*>(out + (size_t)(h * HD + dl) * N + n0 + nq * 4) = o;
}

// ---------------------------------------------------------------------------
// MFMA flash attention, split-K, 4 waves sharing K/V staging.
// Q is PRE-SCALED by log2(e)/sqrt(hd) at its producing GEMM -> softmax runs
// in the exp2 domain (v_exp_f32 native), no per-score multiply.
// PV uses swapped operands mfma(V,P): output cols = queries, so the
// alpha-rescale and 1/l are lane-local (query = lo) -- no broadcast shfls.
// Defer-max (THR=8, log2 domain): skip rescale when tile max doesn't grow.
// Epilogue transposes o via per-wave LDS Tb for coalesced float4 stores.
// OP partials unnormalized; (m, l) per query in ML (log2 domain).
// ---------------------------------------------------------------------------
__global__ __launch_bounds__(256) void attn_mfma_split(
    const bfraw* __restrict__ Qb, const bfraw* __restrict__ Kb,
    const bfraw* __restrict__ Vt, float* __restrict__ OP,
    float* __restrict__ ML, int Lk, int chunk)
{
    __shared__ __attribute__((aligned(16))) short Ks[64][32];
    __shared__ __attribute__((aligned(16))) short Vts[32][72];
    __shared__ __attribute__((aligned(16))) short Ps[4][16][72];
    __shared__ float Tb[4][16][33];
    int t = threadIdx.x;
    int w = t >> 6, l = t & 63;
    int h = blockIdx.y, q0 = blockIdx.x * 64 + w * 16, z = blockIdx.z;
    int lo = l & 15, quad = l >> 4;
    int kb = z * chunk, ke = kb + chunk;

    s8v qf = *reinterpret_cast<const s8v*>(Qb + (size_t)(q0 + lo) * D + h * HD + quad * 8);
    int kswz = (quad ^ ((lo >> 2) & 3)) * 8;   // swizzled k-frag group

    // shared staging: thread t loads one s8v of K and one of V per step
    int skey = t >> 2, spart = t & 3;
    int kcol = (spart ^ ((skey >> 2) & 3)) * 8;
    int sd = t >> 3, svp = t & 7;
    const bfraw* kp = Kb + (size_t)skey * D + h * HD + spart * 8;
    const bfraw* vp = Vt + (size_t)(h * HD + sd) * Lk + svp * 8;

    float m_r = -1e30f, l_r = 0.f;
    f4v o0 = {0.f, 0.f, 0.f, 0.f}, o1 = {0.f, 0.f, 0.f, 0.f};

    for (int k0 = kb; k0 < ke; k0 += 64) {
        s8v kv = *reinterpret_cast<const s8v*>(kp + (size_t)k0 * D);
        s8v vv = *reinterpret_cast<const s8v*>(vp + k0);
        __syncthreads();   // all waves done reading prev tile
        *reinterpret_cast<s8v*>(&Ks[skey][kcol]) = kv;
        *reinterpret_cast<s8v*>(&Vts[sd][svp * 8]) = vv;
        __syncthreads();   // staged data visible

        f4v sc4[4];
        #pragma unroll
        for (int s = 0; s < 4; s++) {
            s8v kf = *reinterpret_cast<const s8v*>(&Ks[lo + 16 * s][kswz]);
            sc4[s] = __builtin_amdgcn_mfma_f32_16x16x32_bf16(kf, qf, (f4v){0.f,0.f,0.f,0.f}, 0, 0, 0);
        }
        // scores already scaled (Q pre-scaled); softmax in exp2 domain
        float cm = -1e30f;
        #pragma unroll
        for (int s = 0; s < 4; s++)
            #pragma unroll
            for (int r = 0; r < 4; r++)
                cm = fmaxf(cm, sc4[s][r]);
        cm = fmaxf(cm, __shfl_xor(cm, 16));
        cm = fmaxf(cm, __shfl_xor(cm, 32));
        bool skip = __all(cm <= m_r + 8.f);
        if (!skip) {
            float mnew = fmaxf(m_r, cm);
            float alpha = __builtin_amdgcn_exp2f(m_r - mnew);  // local: query=lo
            l_r *= alpha;
            #pragma unroll
            for (int r = 0; r < 4; r++) { o0[r] *= alpha; o1[r] *= alpha; }
            m_r = mnew;
        }
        float ls = 0.f;
        #pragma unroll
        for (int s = 0; s < 4; s++) {
            float p0 = __builtin_amdgcn_exp2f(sc4[s][0] - m_r);
            float p1 = __builtin_amdgcn_exp2f(sc4[s][1] - m_r);
            float p2 = __builtin_amdgcn_exp2f(sc4[s][2] - m_r);
            float p3 = __builtin_amdgcn_exp2f(sc4[s][3] - m_r);
            ls += p0 + p1 + p2 + p3;
            ushort4 pk;
            pk.x = f2b(p0); pk.y = f2b(p1); pk.z = f2b(p2); pk.w = f2b(p3);
            *reinterpret_cast<ushort4*>(&Ps[w][lo][s * 16 + quad * 4]) = pk;
        }
        ls += __shfl_xor(ls, 16);
        ls += __shfl_xor(ls, 32);
        l_r += ls;
        #pragma unroll
        for (int kc = 0; kc < 2; kc++) {
            s8v pf = *reinterpret_cast<const s8v*>(&Ps[w][lo][kc * 32 + quad * 8]);
            s8v v0 = *reinterpret_cast<const s8v*>(&Vts[lo][kc * 32 + quad * 8]);
            s8v v1 = *reinterpret_cast<const s8v*>(&Vts[16 + lo][kc * 32 + quad * 8]);
            // swapped: A=V (rows=d), B=P (cols=query) -> D[d][query]
            o0 = __builtin_amdgcn_mfma_f32_16x16x32_bf16(v0, pf, o0, 0, 0, 0);
            o1 = __builtin_amdgcn_mfma_f32_16x16x32_bf16(v1, pf, o1, 0, 0, 0);
        }
    }

    // transpose epilogue: lane holds O[d = quad*4+r (+16)][query = lo]
    #pragma unroll
    for (int r = 0; r < 4; r++) {
        Tb[w][lo][quad * 4 + r]      = o0[r];
        Tb[w][lo][16 + quad * 4 + r] = o1[r];
    }
    // per-wave buffer: same-wave RAW, compiler inserts lgkmcnt wait
    float* Oz = OP + (size_t)z * L * D;
    int ql = l >> 2, dq = (l & 3) * 8;
    float4 u0, u1;
    u0.x = Tb[w][ql][dq + 0]; u0.y = Tb[w][ql][dq + 1];
    u0.z = Tb[w][ql][dq + 2]; u0.w = Tb[w][ql][dq + 3];
    u1.x = Tb[w][ql][dq + 4]; u1.y = Tb[w][ql][dq + 5];
    u1.z = Tb[w][ql][dq + 6]; u1.w = Tb[w][ql][dq + 7];
    *reinterpret_cast<float4*>(Oz + (size_t)(q0 + ql) * D + h * HD + dq)     = u0;
    *reinterpret_cast<float4*>(Oz + (size_t)(q0 + ql) * D + h * HD + dq + 4) = u1;
    if (l < 16) {
        size_t mi = (((size_t)z * NHD + h) * L + q0 + lo) * 2;
        ML[mi]     = m_r;   // log2 domain
        ML[mi + 1] = l_r;
    }
}

// Merge SPL split-K partials: exact online-softmax combine (log2 domain).
// Grid (L), 256 threads; thread t handles head t>>5, dim t&31.
__global__ __launch_bounds__(256) void attn_combine(
    const float* __restrict__ OP, const float* __restrict__ ML,
    float* __restrict__ O)
{
    int q = blockIdx.x, t = threadIdx.x, h = t >> 5;
    float m[SPL], lv[SPL];
    float M = -1e30f;
    #pragma unroll
    for (int s = 0; s < SPL; s++) {
        size_t mi = (((size_t)s * NHD + h) * L + q) * 2;
        m[s]  = ML[mi];
        lv[s] = ML[mi + 1];
        M = fmaxf(M, m[s]);
    }
    float wl = 0.f, acc = 0.f;
    #pragma unroll
    for (int s = 0; s < SPL; s++) {
        float w = __builtin_amdgcn_exp2f(m[s] - M);
        wl  += w * lv[s];
        acc += w * OP[(size_t)s * L * D + (size_t)q * D + t];
    }
    O[(size_t)q * D + t] = acc / wl;
}

// ---------------------------------------------------------------------------
// GroupNorm stats, two-stage. Stage A: grid (32, RCH); each block reduces a
// 96-row x 32-col slab of X [L, FF] to partial (sum, sumsq) in ps.
// ---------------------------------------------------------------------------
__global__ __launch_bounds__(256) void gn_stats_part(
    const float* __restrict__ X, float* __restrict__ ps)
{
    int g = blockIdx.x, rc = blockIdx.y, t = threadIdx.x;
    int cq = (t & 7) * 4;            // col quad within group (0..28)
    int rl = t >> 3;                 // 0..31 row lane
    int r0 = rc * RP;
    float s = 0.f, sq = 0.f;
    #pragma unroll
    for (int p = 0; p < RP / 32; p++) {
        int l = r0 + p * 32 + rl;
        float4 v = *reinterpret_cast<const float4*>(X + (size_t)l * FF + g * 32 + cq);
        s  += v.x + v.y + v.z + v.w;
        sq += v.x*v.x + v.y*v.y + v.z*v.z + v.w*v.w;
    }
    __shared__ float rs[256], rq[256];
    rs[t] = s; rq[t] = sq;
    __syncthreads();
    for (int o = 128; o > 0; o >>= 1) {
        if (t < o) { rs[t] += rs[t + o]; rq[t] += rq[t + o]; }
        __syncthreads();
    }
    if (t == 0) {
        ps[(g * RCH + rc) * 2]     = rs[0];
        ps[(g * RCH + rc) * 2 + 1] = rq[0];
    }
}

// Stage B: one block; thread g<32 folds RCH partials into mean/rstd.
__global__ __launch_bounds__(64) void gn_stats_final(
    const float* __restrict__ ps, float* __restrict__ st)
{
    int g = threadIdx.x;
    if (g < 32) {
        float s = 0.f, sq = 0.f;
        for (int i = 0; i < RCH; i++) {
            s  += ps[(g * RCH + i) * 2];
            sq += ps[(g * RCH + i) * 2 + 1];
        }
        float n = (float)(L * 32);
        float mean = s / n;
        float var  = sq / n - mean * mean;
        st[g * 2]     = mean;
        st[g * 2 + 1] = rsqrtf(var + 1e-5f);
    }
}

// ---------------------------------------------------------------------------
// Fused GN + exact-GELU + depthwise 5x5 conv. Grid (6,6,16):
// block = 8x8 spatial tile x 64 channels; stage 12x12 halo (GN+GELU applied,
// zero-padded AFTER activation) in LDS (36.9 KB); conv from LDS, write Y.
// Lane owns channel c = t&63 -> coalesced global, conflict-free LDS.
// ---------------------------------------------------------------------------
__global__ __launch_bounds__(256) void gn_gelu_dwconv(
    const float* __restrict__ X, const float* __restrict__ st,
    const float* __restrict__ gg, const float* __restrict__ gb,
    const float* __restrict__ Kw, float* __restrict__ Y)
{
    __shared__ float tile[144][64];
    int h0 = blockIdx.x * 8, w0 = blockIdx.y * 8, c0 = blockIdx.z * 64;
    int t = threadIdx.x;
    int c = t & 63;
    int cg = (c0 + c) >> 5;
    float mu = st[2 * cg], rs = st[2 * cg + 1];
    float ga = gg[c0 + c], be = gb[c0 + c];

    for (int i = t; i < 144 * 64; i += 256) {
        int sp = i >> 6;                       // 0..143 (i&63 == c)
        int hy = h0 + (sp / 12) - 2, wx = w0 + (sp % 12) - 2;
        float v = 0.f;
        if (hy >= 0 && hy < HH && wx >= 0 && wx < WWW) {
            float x = X[(size_t)(hy * WWW + wx) * FF + c0 + c];
            x = (x - mu) * rs * ga + be;
            v = 0.5f * x * (1.f + erff(x * 0.70710678118654752f));
        }
        tile[sp][c] = v;
    }
    float kw[25];
    #pragma unroll
    for (int i = 0; i < 25; i++) kw[i] = Kw[(size_t)(c0 + c) * 25 + i];
    __syncthreads();

    int sgrp = t >> 6;                         // 0..3, 16 outputs each
    for (int s = 0; s < 16; s++) {
        int sp = sgrp * 16 + s;                // 0..63
        int oh = sp >> 3, ow = sp & 7;
        float acc = 0.f;
        #pragma unroll
        for (int ky = 0; ky < 5; ky++)
            #pragma unroll
            for (int kx = 0; kx < 5; kx++)
                acc += tile[(oh + ky) * 12 + ow + kx][c] * kw[ky * 5 + kx];
        Y[(size_t)((h0 + oh) * WWW + w0 + ow) * FF + c0 + c] = acc;
    }
}

// ---------------------------------------------------------------------------
extern "C" void kernel_launch(void* const* d_in, const int* in_sizes, int n_in,
                              void* d_out, int out_size, void* d_ws, size_t ws_size,
                              hipStream_t stream)
{
    (void)in_sizes;
    float* out = (float*)d_out;   // reference output dtype is float32

    if (n_in != 34) {
        diag_kernel<<<(out_size + 255) / 256, 256, 0, stream>>>(out, 2000.f, out_size);
        return;
    }

    const float* tgt    = (const float*)d_in[0];
    const float* gK     = (const float*)d_in[1];
    const float* gV     = (const float*)d_in[2];
    const float* lK     = (const float*)d_in[3];
    const float* lV     = (const float*)d_in[4];
    const float* ln1_g  = (const float*)d_in[5];
    const float* ln1_b  = (const float*)d_in[6];
    const float* ln2_g  = (const float*)d_in[7];
    const float* ln2_b  = (const float*)d_in[8];
    const float* ln3_g  = (const float*)d_in[9];
    const float* ln3_b  = (const float*)d_in[10];
    const float* ln4_g  = (const float*)d_in[11];
    const float* ln4_b  = (const float*)d_in[12];
    const float* sa_Wq  = (const float*)d_in[13];
    const float* sa_bq  = (const float*)d_in[14];
    const float* sa_Wk  = (const float*)d_in[15];
    const float* sa_bk  = (const float*)d_in[16];
    const float* sa_Wv  = (const float*)d_in[17];
    const float* sa_bv  = (const float*)d_in[18];
    const float* sa_Wo  = (const float*)d_in[19];
    const float* sa_bo  = (const float*)d_in[20];
    const float* Wq     = (const float*)d_in[21];
    const float* bq     = (const float*)d_in[22];
    const float* lt_Wo  = (const float*)d_in[23];
    const float* lt_bo  = (const float*)d_in[24];
    const float* st_Wo  = (const float*)d_in[25];
    const float* st_bo  = (const float*)d_in[26];
    const float* W1w    = (const float*)d_in[27];
    const float* b1w    = (const float*)d_in[28];
    const float* gn_g   = (const float*)d_in[29];
    const float* gn_b   = (const float*)d_in[30];
    const float* dw_k   = (const float*)d_in[31];
    const float* W2w    = (const float*)d_in[32];
    const float* b2w    = (const float*)d_in[33];

    // Workspace (fp32): t0..t5 [L,D] + X2 [L,FF] + ST.
    // bf16 attention buffers alias X2 (dead until the stage-3 conv):
    //   qb[LD] | kb1[2LD] | vtb1[2LD] | kb2[LD] | vtb2[LD] = 7*LD bf16 (8.26MB)
    // Attention split-K partials: OP = t0..t3 (4*LD fp32, contiguous, dead
    // during each attention); ML lives in X2 slack after the bf16 buffers.
    // gn_stats partials PS reuse the (dead in stage 3) ML slot.
    const size_t LD = (size_t)L * D;
    const size_t NEED = (6 * LD + (size_t)L * FF + 64) * 4;
    float* ws = (float*)d_ws;
    float* t0 = ws + 0 * LD;
    float* t1 = ws + 1 * LD;
    float* t2 = ws + 2 * LD;
    float* t3 = ws + 3 * LD;
    float* t4 = ws + 4 * LD;
    float* t5 = ws + 5 * LD;
    float* X1 = t0;                   // [L,FF], spans t0..t3 (dead in stage 3)
    float* X2 = ws + 6 * LD;          // [L,FF]
    float* ST = X2 + (size_t)L * FF;  // 64 floats
    bfraw* qb   = (bfraw*)X2;
    bfraw* kb1  = qb + LD;            // gK bf16 (2L)
    bfraw* vtb1 = qb + 3 * LD;        // gV^T bf16 (2L)
    bfraw* kb2  = qb + 5 * LD;        // self/st K bf16 (L)
    bfraw* vtb2 = qb + 6 * LD;        // self/st V^T bf16 (L)
    float* OP   = ws;                 // split-K partials: [SPL][L][D] = t0..t3
    float* ML   = X2 + (7 * LD) / 2;  // [SPL][NHD][L][2] = 590KB (slack: 1.18MB)
    float* PS   = ML;                 // gn_stats partials [32][RCH][2] (stage 3)

    if (ws_size < NEED) {
        int wsMiB = (int)(ws_size >> 20); if (wsMiB > 63) wsMiB = 63;
        diag_kernel<<<(out_size + 255) / 256, 256, 0, stream>>>(out, 64.f + (float)wsMiB, out_size);
        return;
    }

    dim3 gDD(L / 32, D / 64);         // (72, 4)
    dim3 gDF(L / 32, FF / 64);        // (72, 16)
    dim3 gATS(L / 64, NHD, SPL);      // (36, 8, 4), 256-thread blocks
    int  cvtLD  = (int)(LD / 1024);
    dim3 gT1(L / 32, NHD);
    dim3 gT2(2 * L / 32, NHD);
    dim3 gGN(32, RCH);                // gn_stats stage A
    dim3 gDW(6, 6, 16);               // fused gn+gelu+dwconv

    // ---- stage 1: self attention ----
    ln_kernel<<<L, 256, 0, stream>>>(tgt, nullptr, ln1_g, ln1_b, t0, nullptr);
    gemm_mfma<<<gDD, 256, 0, stream>>>(t0, sa_Wq, sa_bq, nullptr, t1, qb,  S2LOG, L, D, D);
    gemm_mfma<<<gDD, 256, 0, stream>>>(t0, sa_Wk, sa_bk, nullptr, t2, kb2, 1.f,   L, D, D);
    gemm_mfma<<<gDD, 256, 0, stream>>>(t0, sa_Wv, sa_bv, nullptr, t3, nullptr, 1.f, L, D, D);
    cvtT_kernel<<<gT1, 256, 0, stream>>>(t3, vtb2, L);
    // t0..t3 now dead -> split-K partials
    attn_mfma_split<<<gATS, 256, 0, stream>>>(qb, kb2, vtb2, OP, ML, L, L / SPL);
    attn_combine<<<L, 256, 0, stream>>>(OP, ML, t4);
    gemm_mfma<<<gDD, 256, 0, stream>>>(t4, sa_Wo, sa_bo, tgt, t5, nullptr, 1.f, L, D, D); // t5 = tgt + SA

    // ---- stage 2: long-term + short-term cross-attention ----
    ln_kernel<<<L, 256, 0, stream>>>(t5, nullptr, ln2_g, ln2_b, t0, nullptr);          // curr_V
    gemm_mfma<<<gDD, 256, 0, stream>>>(t0, Wq, bq, nullptr, t1, qb, S2LOG, L, D, D);   // curr_Q (qb scaled)
    ln_kernel<<<L, 256, 0, stream>>>(t1, lK, ln4_g, ln4_b, t2, kb2);                   // k_st (+bf16)
    ln_kernel<<<L, 256, 0, stream>>>(t0, lV, ln4_g, ln4_b, t3, nullptr);               // v_st
    cvtT_kernel<<<gT1, 256, 0, stream>>>(t3, vtb2, L);                                 // frees t3
    cvt_kernel<<<2 * cvtLD, 256, 0, stream>>>(gK, kb1);
    cvtT_kernel<<<gT2, 256, 0, stream>>>(gV, vtb1, 2 * L);
    // t0..t3 now dead -> split-K partials
    attn_mfma_split<<<gATS, 256, 0, stream>>>(qb, kb1, vtb1, OP, ML, 2 * L, 2 * L / SPL);
    attn_combine<<<L, 256, 0, stream>>>(OP, ML, t4);
    gemm_mfma<<<gDD, 256, 0, stream>>>(t4, lt_Wo, lt_bo, t5, t5, nullptr, 1.f, L, D, D);   // t5 += lt
    attn_mfma_split<<<gATS, 256, 0, stream>>>(qb, kb2, vtb2, OP, ML, L, L / SPL);
    attn_combine<<<L, 256, 0, stream>>>(OP, ML, t4);
    gemm_mfma<<<gDD, 256, 0, stream>>>(t4, st_Wo, st_bo, t5, t5, nullptr, 1.f, L, D, D);   // t5 += st

    // ---- stage 3: FFN with fused GN + GELU + depthwise conv ----
    ln_kernel<<<L, 256, 0, stream>>>(t5, nullptr, ln3_g, ln3_b, t4, nullptr);          // ln3 (outside X1)
    gemm_mfma<<<gDF, 256, 0, stream>>>(t4, W1w, b1w, nullptr, X1, nullptr, 1.f, L, FF, D);
    gn_stats_part<<<gGN, 256, 0, stream>>>(X1, PS);
    gn_stats_final<<<1, 64, 0, stream>>>(PS, ST);
    gn_gelu_dwconv<<<gDW, 256, 0, stream>>>(X1, ST, gn_g, gn_b, dw_k, X2);             // X2 = conv out
    gemm_mfma<<<gDD, 256, 0, stream>>>(X2, W2w, b2w, t5, out, nullptr, 1.f, L, D, FF); // out = t5 + FFN
}